// Round 7
// baseline (301.803 us; speedup 1.0000x reference)
//
#include <hip/hip_runtime.h>
#include <cstdint>
#include <cstddef>

typedef unsigned short u16;
typedef __attribute__((ext_vector_type(8))) short short8;      // 8 bf16 (4 VGPRs) MFMA operand
typedef __attribute__((ext_vector_type(4))) float f32x4;       // MFMA 16x16 accumulator
typedef __attribute__((ext_vector_type(4))) float float4v;
typedef __attribute__((ext_vector_type(4))) unsigned short us4;

#define NEMBD 1024
#define NHEADS 16
#define HDIM 64
#define BB 8
#define LL 1024
#define MTOT (BB * LL)

// ---- ws layout (u16 offsets) ----
#define OFF_W 0                       // 4 weight matrices, 1<<20 u16 each (Wq,Wk,Wv,Wp) -- contiguous rows
#define OFF_B (4u << 20)              // 4 biases, 1024 u16 each (bq,bk,bv,bp) -- contiguous
#define OFF_QB (OFF_B + 4096)         // Q projection / attn output, 1<<23 u16
#define OFF_X (OFF_QB + (1u << 23))   // optional bf16 copies of query,key,value
#define WS_NEED_PRE ((size_t)(OFF_X + 3u * (1u << 23)) * 2)  // 75,505,664 B

static __device__ __forceinline__ float bf2f(u16 h) {
    union { unsigned u; float f; } x; x.u = ((unsigned)h) << 16; return x.f;
}
static __device__ __forceinline__ u16 f2bf(float f) {
    union { unsigned u; float f; } x; x.f = f;
    unsigned u = x.u; u += 0x7fffu + ((u >> 16) & 1u);
    return (u16)(u >> 16);
}

// async global->LDS, 16B per lane; LDS dest = wave-uniform base + lane*16
static __device__ __forceinline__ void async_ld16(const void* g, void* lds_base) {
    __builtin_amdgcn_global_load_lds(
        (const __attribute__((address_space(1))) unsigned int*)g,
        (__attribute__((address_space(3))) unsigned int*)lds_base, 16, 0, 0);
}
#define WAIT_ALL() asm volatile("s_waitcnt vmcnt(0) lgkmcnt(0)" ::: "memory")
#define BAR() __builtin_amdgcn_s_barrier()

// ------------------------------------------------------------------
// fp32 -> bf16 conversion pass. Grid-stride over 1024-elem chunks
// (G11: 2048 resident blocks instead of 28676 tiny launches).
__global__ __launch_bounds__(256) void cvt_all(
    const float* __restrict__ Wq, const float* __restrict__ Wk,
    const float* __restrict__ Wv, const float* __restrict__ Wp,
    const float* __restrict__ bq, const float* __restrict__ bk,
    const float* __restrict__ bv, const float* __restrict__ bp,
    const float* __restrict__ xq, const float* __restrict__ xk,
    const float* __restrict__ xv, u16* __restrict__ ws, int nchunks)
{
    for (int c = blockIdx.x; c < nchunks; c += gridDim.x) {
        int blk = c;
        const float* src; u16* dst; float scale = 1.f;
        if (blk < 1024)      { src = Wq; dst = ws + OFF_W;               scale = 0.125f; }
        else if (blk < 2048) { src = Wk; dst = ws + OFF_W + (1u << 20);  blk -= 1024; }
        else if (blk < 3072) { src = Wv; dst = ws + OFF_W + (2u << 20);  blk -= 2048; }
        else if (blk < 4096) { src = Wp; dst = ws + OFF_W + (3u << 20);  blk -= 3072; }
        else if (blk < 4100) {
            int wb = blk - 4096;
            src = (wb == 0) ? bq : (wb == 1) ? bk : (wb == 2) ? bv : bp;
            dst = ws + OFF_B + wb * 1024; scale = (wb == 0) ? 0.125f : 1.f; blk = 0;
        }
        else if (blk < 12292) { src = xq; dst = ws + OFF_X;               blk -= 4100; }
        else if (blk < 20484) { src = xk; dst = ws + OFF_X + (1u << 23);  blk -= 12292; }
        else                  { src = xv; dst = ws + OFF_X + (2u << 23);  blk -= 20484; }
        const int i = blk * 1024 + threadIdx.x * 4;
        float4v f = *(const float4v*)&src[i];
        us4 o;
#pragma unroll
        for (int j = 0; j < 4; j++) o[j] = f2bf(f[j] * scale);
        *(us4*)&dst[i] = o;
    }
}

// ------------------------------------------------------------------
// 8-wave phase-split GEMM (T3+T4+T5): BM=256, BN=128, BK=64, 512 thr.
// Triple-buffered LDS (3 x 48KB = 144KB). Tile t lives in buf[t%3];
// during tile t's two phases we stage tile t+2 into buf[(t+2)%3] (that
// buffer was last read in tile t-1 -> race-free by construction).
// Counted s_waitcnt vmcnt(6) at tile end: tile t+1's 6 loads/wave are
// complete, tile t+2's 6 stay IN FLIGHT across the barrier (T4: never
// drain to 0 in the main loop). Raw s_barrier (not __syncthreads).
// MEASURED R3: 66 us, MfmaUtil 32% (R6 container: 80 us -- cross-container
// noise; within-container deltas only).
// OUTMODE 0: fused QKV routing (z = n0>>10: q->qb, k->kb, v->vtg^T).
// OUTMODE 1: fp32 output (projection).
template <int OUTMODE>
static __device__ __forceinline__ void gemm8_body(
    const u16* __restrict__ X, const u16* __restrict__ W,
    const u16* __restrict__ biasAll, u16* __restrict__ qb, u16* __restrict__ kb,
    u16* __restrict__ vtg, float* __restrict__ Yf, int m0, int n0, u16* sm)
{
    constexpr int K = NEMBD;
    constexpr int TILE = 24 * 1024;     // u16: A 256x64 (16K) + B 128x64 (8K)
    constexpr int NT = K / 64;          // 16 K-tiles
    const int t = threadIdx.x;
    const int wave = t >> 6, lane = t & 63;
    const int quad = lane >> 4, l16 = lane & 15;
    const int wm = (wave >> 1) * 64;    // 4 M-groups of waves
    const int wn = (wave & 1) * 64;     // 2 N-groups
    const int rsub = lane >> 3;                 // staging row within 8-row group
    const int csw = ((lane & 7) ^ rsub) * 8;    // swizzled source col (u16)
    const int swr = l16 & 7;                    // read swizzle key

    f32x4 acc[4][4];
#pragma unroll
    for (int i = 0; i < 4; i++)
#pragma unroll
        for (int j = 0; j < 4; j++) acc[i][j] = (f32x4){0.f, 0.f, 0.f, 0.f};

    // stage half hf (0/1) of K-tile kt into buffer bufi: 3 loads/wave
    auto stage_half = [&](int kt, int bufi, int hf) {
        u16* A = sm + bufi * TILE;
        u16* Bb = A + 16 * 1024;
        const int k0 = kt * 64;
#pragma unroll
        for (int j = 0; j < 2; j++) {
            const int g = wave * 4 + hf * 2 + j;          // A: 32 groups of 8 rows
            async_ld16(X + (size_t)(m0 + g * 8 + rsub) * K + k0 + csw, &A[g * 8 * 64]);
        }
        const int gb = wave * 2 + hf;                     // B: 16 groups
        async_ld16(W + (size_t)(n0 + gb * 8 + rsub) * K + k0 + csw, &Bb[gb * 8 * 64]);
    };

    // compute phase: k-half h of buffer bufi (8 ds_read_b128 + 16 MFMA)
    auto phase = [&](int bufi, int h) {
        const u16* A = sm + bufi * TILE;
        const u16* Bb = A + 16 * 1024;
        short8 a[4], b[4];
#pragma unroll
        for (int i = 0; i < 4; i++) {
            a[i] = *(const short8*)&A[(wm + i * 16 + l16) * 64 + (((h * 4 + quad) ^ swr) * 8)];
            b[i] = *(const short8*)&Bb[(wn + i * 16 + l16) * 64 + (((h * 4 + quad) ^ swr) * 8)];
        }
        __builtin_amdgcn_s_setprio(1);
#pragma unroll
        for (int i = 0; i < 4; i++)
#pragma unroll
            for (int j = 0; j < 4; j++)
                acc[i][j] = __builtin_amdgcn_mfma_f32_16x16x32_bf16(a[i], b[j], acc[i][j], 0, 0, 0);
        __builtin_amdgcn_s_setprio(0);
    };

    // prologue: stage tiles 0 and 1 (12 loads/wave); wait tile 0 only
    stage_half(0, 0, 0); stage_half(0, 0, 1);
    stage_half(1, 1, 0); stage_half(1, 1, 1);
    asm volatile("s_waitcnt vmcnt(6)" ::: "memory");
    BAR();

#pragma unroll
    for (int kt = 0; kt < NT; kt++) {
        const int bufi = kt % 3;
        const int nb = (kt + 2) % 3;
        const bool pf = (kt + 2) < NT;
        // ---- phase 0 ----
        if (pf) stage_half(kt + 2, nb, 0);
        __builtin_amdgcn_sched_barrier(0);
        phase(bufi, 0);
        BAR();
        // ---- phase 1 ----
        if (pf) stage_half(kt + 2, nb, 1);
        __builtin_amdgcn_sched_barrier(0);
        phase(bufi, 1);
        if (pf) asm volatile("s_waitcnt vmcnt(6)" ::: "memory");  // t+1 done, t+2 in flight
        else    asm volatile("s_waitcnt vmcnt(0)" ::: "memory");  // tail drain
        BAR();
    }

    // ---- epilogue. C/D layout: col=lane&15, row=quad*4+reg ----
    if constexpr (OUTMODE == 0) {
        const int nz = n0 >> 10;
        if (nz == 2) {                  // V -> V^T [b][h][d][key]
#pragma unroll
            for (int j = 0; j < 4; j++) {
                const int n = n0 + wn + j * 16 + l16;
                const float bn = bf2f(biasAll[n]);
                const int nl = n & 1023, h = nl >> 6, d = nl & 63;
#pragma unroll
                for (int i = 0; i < 4; i++) {
                    const int mb = m0 + wm + i * 16 + quad * 4;
                    const int b = mb >> 10, key = mb & 1023;
                    us4 pack;
#pragma unroll
                    for (int r = 0; r < 4; r++) pack[r] = f2bf(acc[i][j][r] + bn);
                    *(us4*)&vtg[(size_t)(b * 16 + h) * 65536 + d * 1024 + key] = pack;
                }
            }
        } else {
            u16* Y = (nz == 0) ? qb : kb;
#pragma unroll
            for (int j = 0; j < 4; j++) {
                const int n = n0 + wn + j * 16 + l16;
                const float bn = bf2f(biasAll[n]);
                const int nl = n & 1023;
#pragma unroll
                for (int i = 0; i < 4; i++) {
                    const int mb = m0 + wm + i * 16 + quad * 4;
#pragma unroll
                    for (int r = 0; r < 4; r++)
                        Y[(size_t)(mb + r) * 1024 + nl] = f2bf(acc[i][j][r] + bn);
                }
            }
        }
    } else {
#pragma unroll
        for (int j = 0; j < 4; j++) {
            const int n = n0 + wn + j * 16 + l16;
            const float bn = bf2f(biasAll[n]);
#pragma unroll
            for (int i = 0; i < 4; i++) {
                const int mb = m0 + wm + i * 16 + quad * 4;
#pragma unroll
                for (int r = 0; r < 4; r++)
                    Yf[(size_t)(mb + r) * 1024 + n] = acc[i][j][r] + bn;
            }
        }
    }
}

// Per-z QKV GEMM: M=8192 x N=1024 x K=1024, grid 256 = 1 EXACT round
// (32 m-panels x 8 n-panels, XCD chunk = 4m x 8n: X 2MB + W 2MB per-XCD
// L2 working set). Launched 3x (z=0/1/2) so the top-5 profile slots can
// expose attn/cvt/out durations (measurement round R7).
// nbase = z*1024 carries the global column; routing in gemm8_body keys
// off n0>>10 unchanged.
__global__ __launch_bounds__(512, 1) void gemm_qkv8z(
    const u16* __restrict__ X, const u16* __restrict__ ws, u16* __restrict__ qb,
    u16* __restrict__ kb, u16* __restrict__ vtg, int nbase)
{
    __shared__ __align__(16) u16 sm[3 * 24 * 1024];   // 144 KiB
    const int bid = blockIdx.x;
    const int swz = (bid & 7) * 32 + (bid >> 3);      // 256 = 8 XCD-chunks x 32
    const int m0 = (swz >> 3) * 256;                  // 0..31 m-panels
    const int n0 = nbase + (swz & 7) * 128;           // 8 n-panels within z
    gemm8_body<0>(X, ws + OFF_W, ws + OFF_B, qb, kb, vtg, nullptr, m0, n0, sm);
}

// ------------------------------------------------------------------
// 2-wave BK=32 output-projection GEMM (R5 body; measured-passing).
static __device__ __forceinline__ void gemm32_out(
    const u16* __restrict__ X, const u16* __restrict__ W,
    const u16* __restrict__ biasAll, float* __restrict__ Yf,
    int m0, int n0, u16* sm)
{
    constexpr int NT = 32;              // K-tiles of 32
    const int t = threadIdx.x;
    const int wave = t >> 6, lane = t & 63;
    const int quad = lane >> 4, l16 = lane & 15;
    const int rl = lane >> 2;                         // staging row within 16-row group
    const int csrc = (((lane & 3) ^ ((lane >> 3) & 3)) * 8);  // swizzled src col (u16)
    const int swk = (l16 >> 1) & 3;                   // read swizzle key

    f32x4 acc[8][4];
#pragma unroll
    for (int i = 0; i < 8; i++)
#pragma unroll
        for (int j = 0; j < 4; j++) acc[i][j] = (f32x4){0.f, 0.f, 0.f, 0.f};

    auto stage_half = [&](int kt, int bufi, int hf) {
        u16* A = sm + bufi * 8192;      // A: 128x32 u16
        u16* Bb = A + 4096;             // B: 128x32 u16
        const int k0 = kt * 32;
#pragma unroll
        for (int rr = 0; rr < 2; rr++) {
            const int row = hf * 64 + rr * 32 + wave * 16;
            async_ld16(X + (size_t)(m0 + row + rl) * NEMBD + k0 + csrc, &A[row * 32]);
        }
#pragma unroll
        for (int rr = 0; rr < 2; rr++) {
            const int row = hf * 64 + rr * 32 + wave * 16;
            async_ld16(W + (size_t)(n0 + row + rl) * NEMBD + k0 + csrc, &Bb[row * 32]);
        }
    };

    stage_half(0, 0, 0); stage_half(0, 0, 1);
    stage_half(1, 1, 0); stage_half(1, 1, 1);
    asm volatile("s_waitcnt vmcnt(8)" ::: "memory");
    BAR();

    short8 bfr[4], a[4];
    int cb = 0;
    for (int kt = 0; kt < NT; kt++) {
        const int pb = (cb == 0) ? 2 : cb - 1;        // (cb+2)%3
        const u16* A = sm + cb * 8192;
        const u16* Bb = A + 4096;
        const bool pf = kt < NT - 2;

        if (pf) stage_half(kt + 2, pb, 0);
#pragma unroll
        for (int j = 0; j < 4; j++)
            bfr[j] = *(const short8*)&Bb[(wave * 64 + j * 16 + l16) * 32 + ((quad ^ swk) * 8)];
#pragma unroll
        for (int i = 0; i < 4; i++)
            a[i] = *(const short8*)&A[(i * 16 + l16) * 32 + ((quad ^ swk) * 8)];
        __builtin_amdgcn_sched_barrier(0);
        BAR();
        asm volatile("s_waitcnt lgkmcnt(0)" ::: "memory");
        __builtin_amdgcn_sched_barrier(0);
        __builtin_amdgcn_s_setprio(1);
#pragma unroll
        for (int i = 0; i < 4; i++)
#pragma unroll
            for (int j = 0; j < 4; j++)
                acc[i][j] = __builtin_amdgcn_mfma_f32_16x16x32_bf16(a[i], bfr[j], acc[i][j], 0, 0, 0);
        __builtin_amdgcn_s_setprio(0);
        BAR();

        if (pf) stage_half(kt + 2, pb, 1);
#pragma unroll
        for (int i = 0; i < 4; i++)
            a[i] = *(const short8*)&A[((i + 4) * 16 + l16) * 32 + ((quad ^ swk) * 8)];
        __builtin_amdgcn_sched_barrier(0);
        BAR();
        asm volatile("s_waitcnt lgkmcnt(0)" ::: "memory");
        __builtin_amdgcn_sched_barrier(0);
        __builtin_amdgcn_s_setprio(1);
#pragma unroll
        for (int i = 0; i < 4; i++)
#pragma unroll
            for (int j = 0; j < 4; j++)
                acc[i + 4][j] = __builtin_amdgcn_mfma_f32_16x16x32_bf16(a[i], bfr[j], acc[i + 4][j], 0, 0, 0);
        __builtin_amdgcn_s_setprio(0);
        if (pf) asm volatile("s_waitcnt vmcnt(8)" ::: "memory");
        else    asm volatile("s_waitcnt vmcnt(0)" ::: "memory");
        BAR();
        cb = (cb == 2) ? 0 : cb + 1;
    }

#pragma unroll
    for (int j = 0; j < 4; j++) {
        const int n = n0 + wave * 64 + j * 16 + l16;
        const float bn = bf2f(biasAll[n]);
#pragma unroll
        for (int i = 0; i < 8; i++) {
            const int mb = m0 + i * 16 + quad * 4;
#pragma unroll
            for (int r = 0; r < 4; r++)
                Yf[(size_t)(mb + r) * 1024 + n] = acc[i][j][r] + bn;
        }
    }
}

// Output projection: M=8192 x N=1024, 64x8 grid = 512 blocks = 2/CU exact.
__global__ __launch_bounds__(128, 2) void gemm_out9(
    const u16* __restrict__ X, const u16* __restrict__ ws, float* __restrict__ Y)
{
    __shared__ __align__(16) u16 sm[3 * 8192];        // 48 KiB
    const int bid = blockIdx.x;
    const int xcd = bid & 7, i = bid >> 3;            // i in 0..63
    const int mp = xcd * 8 + i / 8;                   // 0..63
    const int np = i % 8;                             // 0..7
    gemm32_out(X, ws + OFF_W + (size_t)3 * (1u << 20), ws + OFF_B + 3 * 1024,
               Y, mp * 128, np * 128, sm);
}

// ------------------------------------------------------------------
// Legacy 128^2 2-phase body -- kept only for the fp32-X fallback path.
template <typename TX, typename TY>
static __device__ __forceinline__ void gemm_body64(
    const TX* __restrict__ X, const u16* __restrict__ W,
    const u16* __restrict__ bias, TY* __restrict__ Y, int vtrans,
    u16* As, u16* Bs)   // each 2 * 128*64 u16 (double-buffered)
{
    constexpr int K = NEMBD, N = NEMBD;
    constexpr int BUF = 128 * 64;
    const int t = threadIdx.x;
    const int wave = t >> 6, lane = t & 63;
    const int quad = lane >> 4, l16 = lane & 15;
    const int flat = blockIdx.x + 8 * blockIdx.y;
    const int swz = (flat & 7) * 64 + (flat >> 3);
    const int m0 = (swz >> 3) * 128, n0 = (swz & 7) * 128;
    const int wm = (wave >> 1) * 64, wn = (wave & 1) * 64;
    const int rsub = lane >> 3;
    const int csw = ((lane & 7) ^ rsub) * 8;
    const int swr = l16 & 7;
    const int frow = t >> 1, fc0 = (t & 1) * 4;

    f32x4 acc[4][4];
#pragma unroll
    for (int i = 0; i < 4; i++)
#pragma unroll
        for (int j = 0; j < 4; j++) acc[i][j] = (f32x4){0.f, 0.f, 0.f, 0.f};

    auto stage = [&](int k0, int bufi) {
        u16* A = As + bufi * BUF;
        u16* Bb = Bs + bufi * BUF;
        if constexpr (__is_same(TX, u16)) {
#pragma unroll
            for (int j = 0; j < 4; j++) {
                const int g = wave * 4 + j;
                async_ld16(X + (size_t)(m0 + g * 8 + rsub) * K + k0 + csw, &A[g * 8 * 64]);
            }
        } else {
#pragma unroll
            for (int c = 0; c < 4; c++) {
                const int lc = fc0 + c;
                float4v f0 = *(const float4v*)&X[(size_t)(m0 + frow) * K + k0 + lc * 8];
                float4v f1 = *(const float4v*)&X[(size_t)(m0 + frow) * K + k0 + lc * 8 + 4];
                __align__(16) u16 tmp[8];
#pragma unroll
                for (int j = 0; j < 4; j++) { tmp[j] = f2bf(f0[j]); tmp[4 + j] = f2bf(f1[j]); }
                *(short8*)&A[frow * 64 + (lc ^ (frow & 7)) * 8] = *(const short8*)tmp;
            }
        }
#pragma unroll
        for (int j = 0; j < 4; j++) {
            const int g = wave * 4 + j;
            async_ld16(W + (size_t)(n0 + g * 8 + rsub) * K + k0 + csw, &Bb[g * 8 * 64]);
        }
    };

    stage(0, 0);
    WAIT_ALL();
    __syncthreads();

    int cur = 0;
    for (int k0 = 0; k0 < K; k0 += 64) {
        if (k0 + 64 < K) stage(k0 + 64, cur ^ 1);
        const u16* A = As + cur * BUF;
        const u16* Bb = Bs + cur * BUF;
#pragma unroll
        for (int h = 0; h < 2; h++) {
            short8 a[4], b[4];
#pragma unroll
            for (int i = 0; i < 4; i++) {
                a[i] = *(const short8*)&A[(wm + i * 16 + l16) * 64 + (((h * 4 + quad) ^ swr) * 8)];
                b[i] = *(const short8*)&Bb[(wn + i * 16 + l16) * 64 + (((h * 4 + quad) ^ swr) * 8)];
            }
#pragma unroll
            for (int i = 0; i < 4; i++)
#pragma unroll
                for (int j = 0; j < 4; j++)
                    acc[i][j] = __builtin_amdgcn_mfma_f32_16x16x32_bf16(a[i], b[j], acc[i][j], 0, 0, 0);
        }
        WAIT_ALL();
        __syncthreads();
        cur ^= 1;
    }

    if (vtrans) {
        u16* VT = (u16*)Y;
#pragma unroll
        for (int j = 0; j < 4; j++) {
            const int n = n0 + wn + j * 16 + l16;
            const float bn = bf2f(bias[n]);
            const int h = n >> 6, d = n & 63;
#pragma unroll
            for (int i = 0; i < 4; i++) {
                const int mb = m0 + wm + i * 16 + quad * 4;
                const int b = mb >> 10, key = mb & 1023;
                us4 pack;
#pragma unroll
                for (int r = 0; r < 4; r++) pack[r] = f2bf(acc[i][j][r] + bn);
                *(us4*)&VT[(size_t)(b * 16 + h) * 65536 + d * 1024 + key] = pack;
            }
        }
    } else {
#pragma unroll
        for (int j = 0; j < 4; j++) {
            const int n = n0 + wn + j * 16 + l16;
            const float bn = bf2f(bias[n]);
#pragma unroll
            for (int i = 0; i < 4; i++) {
                const int mb = m0 + wm + i * 16 + quad * 4;
#pragma unroll
                for (int r = 0; r < 4; r++) {
                    float v = acc[i][j][r] + bn;
                    if constexpr (__is_same(TY, u16)) Y[(size_t)(mb + r) * N + n] = f2bf(v);
                    else                              Y[(size_t)(mb + r) * N + n] = v;
                }
            }
        }
    }
}

// QKV, fp32-X fallback (in-GEMM convert)
__global__ __launch_bounds__(256) void gemm_qkv_f(
    const float* __restrict__ xq, const float* __restrict__ xk, const float* __restrict__ xv,
    const u16* __restrict__ ws, u16* __restrict__ qb, u16* __restrict__ kb,
    u16* __restrict__ vtg)
{
    __shared__ __align__(16) u16 As[2 * 128 * 64];
    __shared__ __align__(16) u16 Bs[2 * 128 * 64];
    const int z = blockIdx.z;
    const float* X = (z == 0) ? xq : (z == 1) ? xk : xv;
    const u16* W = ws + OFF_W + (size_t)z * (1u << 20);
    const u16* bias = ws + OFF_B + z * 1024;
    u16* Y = (z == 0) ? qb : (z == 1) ? kb : vtg;
    gemm_body64<float, u16>(X, W, bias, Y, z == 2 ? 1 : 0, As, Bs);
}

// ------------------------------------------------------------------
// Flash attention v5: work-balanced query-tile PAIRING + double-buffered
// prefetch (unchanged).
__global__ __launch_bounds__(256, 2) void attn_fused(
    const u16* __restrict__ Qp, const u16* __restrict__ Kp,
    const u16* __restrict__ Vtg, u16* __restrict__ Yp)
{
    __shared__ __align__(16) u16 Kl[2][64 * 64];    // [buf][key][d], chunk-swizzled
    __shared__ __align__(16) u16 Vt[2][64 * 64];    // [buf][d][key], chunk-swizzled
    __shared__ __align__(16) u16 Pl[4 * 64 * 72];   // per-wave P: rows 0-31 tile A, 32-63 tile B

    const int t = threadIdx.x;
    const int wave = t >> 6, lane = t & 63;
    const int quad = lane >> 4, l16 = lane & 15;
    const int bh = blockIdx.y;
    const int b = bh >> 4, h = bh & 15;
    const int p = blockIdx.x;                       // pair index 0..3
    const int qtA = p, qtB = 7 - p;
    const int q0A = qtA * 128 + wave * 32;
    const int q0B = qtB * 128 + wave * 32;

    const u16* Qb = Qp + (size_t)b * LL * NEMBD + h * HDIM;
    const u16* Kb = Kp + (size_t)b * LL * NEMBD + h * HDIM;
    const u16* Vb = Vtg + (size_t)bh * 65536;       // [d][key]

    short8 aqA[2][2], aqB[2][2];
#pragma unroll
    for (int m = 0; m < 2; m++) {
        aqA[m][0] = *(const short8*)(Qb + (size_t)(q0A + m * 16 + l16) * NEMBD + quad * 8);
        aqA[m][1] = *(const short8*)(Qb + (size_t)(q0A + m * 16 + l16) * NEMBD + 32 + quad * 8);
        aqB[m][0] = *(const short8*)(Qb + (size_t)(q0B + m * 16 + l16) * NEMBD + quad * 8);
        aqB[m][1] = *(const short8*)(Qb + (size_t)(q0B + m * 16 + l16) * NEMBD + 32 + quad * 8);
    }

    f32x4 accA[2][4], accB[2][4];
#pragma unroll
    for (int m = 0; m < 2; m++)
#pragma unroll
        for (int n = 0; n < 4; n++) {
            accA[m][n] = (f32x4){0.f, 0.f, 0.f, 0.f};
            accB[m][n] = (f32x4){0.f, 0.f, 0.f, 0.f};
        }
    float lsA[2][4] = {{0.f, 0.f, 0.f, 0.f}, {0.f, 0.f, 0.f, 0.f}};
    float lsB[2][4] = {{0.f, 0.f, 0.f, 0.f}, {0.f, 0.f, 0.f, 0.f}};

    const int rsub = lane >> 3;
    const int csw8 = ((lane & 7) ^ rsub) * 8;
    const int swr = l16 & 7;
    u16* pw = &Pl[wave * 64 * 72];

    const int ktiles  = 2 * qtB + 2;
    const int ktilesA = 2 * qtA + 2;

    auto stageKV = [&](int kbase, int bufi) {
#pragma unroll
        for (int j = 0; j < 2; j++) {
            const int g0 = wave * 16 + j * 8;
            async_ld16(Kb + (size_t)(kbase + g0 + rsub) * NEMBD + csw8, &Kl[bufi][g0 * 64]);
            async_ld16(Vb + (size_t)(g0 + rsub) * LL + kbase + csw8, &Vt[bufi][g0 * 64]);
        }
    };

    auto qk = [&](const short8 (&aq)[2][2], int q0w, int kbase, const u16* KlC,
                  u16* pwT, float (&lsum)[2][4]) {
#pragma unroll
        for (int m = 0; m < 2; m++) {
            const int qlo = q0w + m * 16;
            if (kbase > qlo + 15) continue;
            const bool dg = (kbase + 63 > qlo);
#pragma unroll
            for (int s = 0; s < 4; s++) {
                const int key = s * 16 + l16;
                const short8 bk0 = *(const short8*)&KlC[key * 64 + ((quad ^ swr) * 8)];
                const short8 bk1 = *(const short8*)&KlC[key * 64 + (((quad + 4) ^ swr) * 8)];
                f32x4 ss = (f32x4){0.f, 0.f, 0.f, 0.f};
                ss = __builtin_amdgcn_mfma_f32_16x16x32_bf16(aq[m][0], bk0, ss, 0, 0, 0);
                ss = __builtin_amdgcn_mfma_f32_16x16x32_bf16(aq[m][1], bk1, ss, 0, 0, 0);
#pragma unroll
                for (int r = 0; r < 4; r++) {
                    float e = __expf(ss[r]);
                    if (dg && (kbase + key > qlo + quad * 4 + r)) e = 0.f;
                    lsum[m][r] += e;
                    pwT[(m * 16 + quad * 4 + r) * 72 + key] = f2bf(e);
                }
            }
        }
    };

    auto pv = [&](f32x4 (&acc)[2][4], int q0w, int kbase, const u16* pwT,
                  const short8 (&bv)[4][2]) {
#pragma unroll
        for (int m = 0; m < 2; m++) {
            if (kbase > q0w + m * 16 + 15) continue;
            const short8 ap0 = *(const short8*)&pwT[(m * 16 + l16) * 72 + quad * 8];
            const short8 ap1 = *(const short8*)&pwT[(m * 16 + l16) * 72 + 32 + quad * 8];
#pragma unroll
            for (int n = 0; n < 4; n++) {
                acc[m][n] = __builtin_amdgcn_mfma_f32_16x16x32_bf16(ap0, bv[n][0], acc[m][n], 0, 0, 0);
                acc[m][n] = __builtin_amdgcn_mfma_f32_16x16x32_bf16(ap1, bv[n][1], acc[m][n], 0, 0, 0);
            }
        }
    };

    stageKV(0, 0);
    WAIT_ALL();
    __syncthreads();

    int cur = 0;
    for (int kt = 0; kt < ktiles; kt++) {
        const int kbase = kt * 64;
        if (kt + 1 < ktiles) stageKV(kbase + 64, cur ^ 1);

        const u16* KlC = &Kl[cur][0];
        const u16* VtC = &Vt[cur][0];

        qk(aqB, q0B, kbase, KlC, pw + 32 * 72, lsB);
        if (kt < ktilesA) qk(aqA, q0A, kbase, KlC, pw, lsA);
        asm volatile("s_waitcnt lgkmcnt(0)" ::: "memory");

        const bool actB = (kbase <= q0B + 31);
        const bool actA = (kt < ktilesA) && (kbase <= q0A + 31);
        if (actA || actB) {
            short8 bv[4][2];
#pragma unroll
            for (int n = 0; n < 4; n++) {
                const int drow = (n * 16 + l16) * 64;
                bv[n][0] = *(const short8*)&VtC[drow + ((quad ^ swr) * 8)];
                bv[n][1] = *(const short8*)&VtC[drow + (((quad + 4) ^ swr) * 8)];
            }
            __builtin_amdgcn_s_setprio(1);
            if (actB) pv(accB, q0B, kbase, pw + 32 * 72, bv);
            if (actA) pv(accA, q0A, kbase, pw, bv);
            __builtin_amdgcn_s_setprio(0);
        }

        WAIT_ALL();
        __syncthreads();
        cur ^= 1;
    }

    u16* Yb = Yp + (size_t)b * LL * NEMBD + h * HDIM;
    auto epi = [&](f32x4 (&acc)[2][4], float (&lsum)[2][4], int q0w) {
#pragma unroll
        for (int m = 0; m < 2; m++) {
#pragma unroll
            for (int r = 0; r < 4; r++) {
                float lr = lsum[m][r];
                lr += __shfl_xor(lr, 1); lr += __shfl_xor(lr, 2);
                lr += __shfl_xor(lr, 4); lr += __shfl_xor(lr, 8);
                const float inv = 1.f / lr;
                const int q = q0w + m * 16 + quad * 4 + r;
#pragma unroll
                for (int n = 0; n < 4; n++)
                    Yb[(size_t)q * NEMBD + n * 16 + l16] = f2bf(acc[m][n][r] * inv);
            }
        }
    };
    epi(accA, lsA, q0A);
    epi(accB, lsB, q0B);
}

// ------------------------------------------------------------------
extern "C" void kernel_launch(void* const* d_in, const int* in_sizes, int n_in,
                              void* d_out, int out_size, void* d_ws, size_t ws_size,
                              hipStream_t stream)
{
    const float* key   = (const float*)d_in[0];
    const float* value = (const float*)d_in[1];
    const float* query = (const float*)d_in[2];
    const float* Wk = (const float*)d_in[3];
    const float* bk = (const float*)d_in[4];
    const float* Wq = (const float*)d_in[5];
    const float* bq = (const float*)d_in[6];
    const float* Wv = (const float*)d_in[7];
    const float* bv = (const float*)d_in[8];
    const float* Wp = (const float*)d_in[9];
    const float* bp = (const float*)d_in[10];

    u16* ws = (u16*)d_ws;
    u16* qb = ws + OFF_QB;                       // Q proj; also attn output (alias-safe)
    u16* kb = (u16*)d_out;                       // K proj in d_out
    u16* vtg = (u16*)d_out + (1u << 23);         // V^T [b][h][d][key] in d_out

    const bool preX = ws_size >= WS_NEED_PRE;    // constant across calls -> graph-safe

    cvt_all<<<2048, 256, 0, stream>>>(
        Wq, Wk, Wv, Wp, bq, bk, bv, bp, query, key, value, ws, preX ? 28676 : 4100);

    if (preX) {
        const u16* xq = ws + OFF_X;
        const u16* xk = ws + OFF_X + (1u << 23);
        const u16* xv = ws + OFF_X + (2u << 23);
        gemm_qkv8z<<<256, 512, 0, stream>>>(xq, ws, qb, kb, vtg, 0);
        gemm_qkv8z<<<256, 512, 0, stream>>>(xk, ws, qb, kb, vtg, 1024);
        gemm_qkv8z<<<256, 512, 0, stream>>>(xv, ws, qb, kb, vtg, 2048);
    } else {
        gemm_qkv_f<<<dim3(8, 64, 3), 256, 0, stream>>>(query, key, value, ws, qb, kb, vtg);
    }

    attn_fused<<<dim3(4, 128), 256, 0, stream>>>(qb, kb, vtg, qb);

    gemm_out9<<<512, 128, 0, stream>>>(qb, ws, (float*)d_out);
}

// Round 8
// 296.407 us; speedup vs baseline: 1.0182x; 1.0182x over previous
//
#include <hip/hip_runtime.h>
#include <cstdint>
#include <cstddef>

typedef unsigned short u16;
typedef __attribute__((ext_vector_type(8))) short short8;      // 8 bf16 (4 VGPRs) MFMA operand
typedef __attribute__((ext_vector_type(4))) float f32x4;       // MFMA 16x16 accumulator
typedef __attribute__((ext_vector_type(4))) float float4v;
typedef __attribute__((ext_vector_type(4))) unsigned short us4;

#define NEMBD 1024
#define NHEADS 16
#define HDIM 64
#define BB 8
#define LL 1024
#define MTOT (BB * LL)

// ---- ws layout (u16 offsets) ----
#define OFF_W 0                       // 4 weight matrices, 1<<20 u16 each (Wq,Wk,Wv,Wp) -- contiguous rows
#define OFF_B (4u << 20)              // 4 biases, 1024 u16 each (bq,bk,bv,bp) -- contiguous
#define OFF_QB (OFF_B + 4096)         // Q projection / attn output, 1<<23 u16
#define OFF_X (OFF_QB + (1u << 23))   // optional bf16 copies of query,key,value
#define WS_NEED_PRE ((size_t)(OFF_X + 3u * (1u << 23)) * 2)  // 75,505,664 B

// Q pre-scale: 1/sqrt(64) * log2(e) -- attn uses exp2f (saves the mul in expf)
#define QSCALE 0.18033688f

static __device__ __forceinline__ float bf2f(u16 h) {
    union { unsigned u; float f; } x; x.u = ((unsigned)h) << 16; return x.f;
}
static __device__ __forceinline__ u16 f2bf(float f) {
    union { unsigned u; float f; } x; x.f = f;
    unsigned u = x.u; u += 0x7fffu + ((u >> 16) & 1u);
    return (u16)(u >> 16);
}

// async global->LDS, 16B per lane; LDS dest = wave-uniform base + lane*16
static __device__ __forceinline__ void async_ld16(const void* g, void* lds_base) {
    __builtin_amdgcn_global_load_lds(
        (const __attribute__((address_space(1))) unsigned int*)g,
        (__attribute__((address_space(3))) unsigned int*)lds_base, 16, 0, 0);
}
#define WAIT_ALL() asm volatile("s_waitcnt vmcnt(0) lgkmcnt(0)" ::: "memory")
#define BAR() __builtin_amdgcn_s_barrier()

// ------------------------------------------------------------------
// fp32 -> bf16 conversion pass. Grid-stride over 1024-elem chunks.
__global__ __launch_bounds__(256) void cvt_all(
    const float* __restrict__ Wq, const float* __restrict__ Wk,
    const float* __restrict__ Wv, const float* __restrict__ Wp,
    const float* __restrict__ bq, const float* __restrict__ bk,
    const float* __restrict__ bv, const float* __restrict__ bp,
    const float* __restrict__ xq, const float* __restrict__ xk,
    const float* __restrict__ xv, u16* __restrict__ ws, int nchunks)
{
    for (int c = blockIdx.x; c < nchunks; c += gridDim.x) {
        int blk = c;
        const float* src; u16* dst; float scale = 1.f;
        if (blk < 1024)      { src = Wq; dst = ws + OFF_W;               scale = QSCALE; }
        else if (blk < 2048) { src = Wk; dst = ws + OFF_W + (1u << 20);  blk -= 1024; }
        else if (blk < 3072) { src = Wv; dst = ws + OFF_W + (2u << 20);  blk -= 2048; }
        else if (blk < 4096) { src = Wp; dst = ws + OFF_W + (3u << 20);  blk -= 3072; }
        else if (blk < 4100) {
            int wb = blk - 4096;
            src = (wb == 0) ? bq : (wb == 1) ? bk : (wb == 2) ? bv : bp;
            dst = ws + OFF_B + wb * 1024; scale = (wb == 0) ? QSCALE : 1.f; blk = 0;
        }
        else if (blk < 12292) { src = xq; dst = ws + OFF_X;               blk -= 4100; }
        else if (blk < 20484) { src = xk; dst = ws + OFF_X + (1u << 23);  blk -= 12292; }
        else                  { src = xv; dst = ws + OFF_X + (2u << 23);  blk -= 20484; }
        const int i = blk * 1024 + threadIdx.x * 4;
        float4v f = *(const float4v*)&src[i];
        us4 o;
#pragma unroll
        for (int j = 0; j < 4; j++) o[j] = f2bf(f[j] * scale);
        *(us4*)&dst[i] = o;
    }
}

// ------------------------------------------------------------------
// 8-wave phase-split GEMM (T3+T4+T5): BM=256, BN=128, BK=64, 512 thr.
// Triple-buffered LDS, counted vmcnt(6), raw s_barrier. MEASURED R3: 66us.
// OUTMODE 0: fused QKV routing (z = n0>>10). OUTMODE 1: fp32 output.
template <int OUTMODE>
static __device__ __forceinline__ void gemm8_body(
    const u16* __restrict__ X, const u16* __restrict__ W,
    const u16* __restrict__ biasAll, u16* __restrict__ qb, u16* __restrict__ kb,
    u16* __restrict__ vtg, float* __restrict__ Yf, int m0, int n0, u16* sm)
{
    constexpr int K = NEMBD;
    constexpr int TILE = 24 * 1024;     // u16: A 256x64 (16K) + B 128x64 (8K)
    constexpr int NT = K / 64;          // 16 K-tiles
    const int t = threadIdx.x;
    const int wave = t >> 6, lane = t & 63;
    const int quad = lane >> 4, l16 = lane & 15;
    const int wm = (wave >> 1) * 64;    // 4 M-groups of waves
    const int wn = (wave & 1) * 64;     // 2 N-groups
    const int rsub = lane >> 3;                 // staging row within 8-row group
    const int csw = ((lane & 7) ^ rsub) * 8;    // swizzled source col (u16)
    const int swr = l16 & 7;                    // read swizzle key

    f32x4 acc[4][4];
#pragma unroll
    for (int i = 0; i < 4; i++)
#pragma unroll
        for (int j = 0; j < 4; j++) acc[i][j] = (f32x4){0.f, 0.f, 0.f, 0.f};

    auto stage_half = [&](int kt, int bufi, int hf) {
        u16* A = sm + bufi * TILE;
        u16* Bb = A + 16 * 1024;
        const int k0 = kt * 64;
#pragma unroll
        for (int j = 0; j < 2; j++) {
            const int g = wave * 4 + hf * 2 + j;          // A: 32 groups of 8 rows
            async_ld16(X + (size_t)(m0 + g * 8 + rsub) * K + k0 + csw, &A[g * 8 * 64]);
        }
        const int gb = wave * 2 + hf;                     // B: 16 groups
        async_ld16(W + (size_t)(n0 + gb * 8 + rsub) * K + k0 + csw, &Bb[gb * 8 * 64]);
    };

    auto phase = [&](int bufi, int h) {
        const u16* A = sm + bufi * TILE;
        const u16* Bb = A + 16 * 1024;
        short8 a[4], b[4];
#pragma unroll
        for (int i = 0; i < 4; i++) {
            a[i] = *(const short8*)&A[(wm + i * 16 + l16) * 64 + (((h * 4 + quad) ^ swr) * 8)];
            b[i] = *(const short8*)&Bb[(wn + i * 16 + l16) * 64 + (((h * 4 + quad) ^ swr) * 8)];
        }
        __builtin_amdgcn_s_setprio(1);
#pragma unroll
        for (int i = 0; i < 4; i++)
#pragma unroll
            for (int j = 0; j < 4; j++)
                acc[i][j] = __builtin_amdgcn_mfma_f32_16x16x32_bf16(a[i], b[j], acc[i][j], 0, 0, 0);
        __builtin_amdgcn_s_setprio(0);
    };

    stage_half(0, 0, 0); stage_half(0, 0, 1);
    stage_half(1, 1, 0); stage_half(1, 1, 1);
    asm volatile("s_waitcnt vmcnt(6)" ::: "memory");
    BAR();

#pragma unroll
    for (int kt = 0; kt < NT; kt++) {
        const int bufi = kt % 3;
        const int nb = (kt + 2) % 3;
        const bool pf = (kt + 2) < NT;
        if (pf) stage_half(kt + 2, nb, 0);
        __builtin_amdgcn_sched_barrier(0);
        phase(bufi, 0);
        BAR();
        if (pf) stage_half(kt + 2, nb, 1);
        __builtin_amdgcn_sched_barrier(0);
        phase(bufi, 1);
        if (pf) asm volatile("s_waitcnt vmcnt(6)" ::: "memory");  // t+1 done, t+2 in flight
        else    asm volatile("s_waitcnt vmcnt(0)" ::: "memory");  // tail drain
        BAR();
    }

    // ---- epilogue. C/D layout: col=lane&15, row=quad*4+reg ----
    if constexpr (OUTMODE == 0) {
        const int nz = n0 >> 10;
        if (nz == 2) {                  // V -> V^T [b][h][d][key]
#pragma unroll
            for (int j = 0; j < 4; j++) {
                const int n = n0 + wn + j * 16 + l16;
                const float bn = bf2f(biasAll[n]);
                const int nl = n & 1023, h = nl >> 6, d = nl & 63;
#pragma unroll
                for (int i = 0; i < 4; i++) {
                    const int mb = m0 + wm + i * 16 + quad * 4;
                    const int b = mb >> 10, key = mb & 1023;
                    us4 pack;
#pragma unroll
                    for (int r = 0; r < 4; r++) pack[r] = f2bf(acc[i][j][r] + bn);
                    *(us4*)&vtg[(size_t)(b * 16 + h) * 65536 + d * 1024 + key] = pack;
                }
            }
        } else {
            u16* Y = (nz == 0) ? qb : kb;
#pragma unroll
            for (int j = 0; j < 4; j++) {
                const int n = n0 + wn + j * 16 + l16;
                const float bn = bf2f(biasAll[n]);
                const int nl = n & 1023;
#pragma unroll
                for (int i = 0; i < 4; i++) {
                    const int mb = m0 + wm + i * 16 + quad * 4;
#pragma unroll
                    for (int r = 0; r < 4; r++)
                        Y[(size_t)(mb + r) * 1024 + nl] = f2bf(acc[i][j][r] + bn);
                }
            }
        }
    } else {
#pragma unroll
        for (int j = 0; j < 4; j++) {
            const int n = n0 + wn + j * 16 + l16;
            const float bn = bf2f(biasAll[n]);
#pragma unroll
            for (int i = 0; i < 4; i++) {
                const int mb = m0 + wm + i * 16 + quad * 4;
#pragma unroll
                for (int r = 0; r < 4; r++)
                    Yf[(size_t)(mb + r) * 1024 + n] = acc[i][j][r] + bn;
            }
        }
    }
}

// Per-z QKV GEMM: M=8192 x N=1024 x K=1024, grid 256 = 1 exact round.
__global__ __launch_bounds__(512, 1) void gemm_qkv8z(
    const u16* __restrict__ X, const u16* __restrict__ ws, u16* __restrict__ qb,
    u16* __restrict__ kb, u16* __restrict__ vtg, int nbase)
{
    __shared__ __align__(16) u16 sm[3 * 24 * 1024];   // 144 KiB
    const int bid = blockIdx.x;
    const int swz = (bid & 7) * 32 + (bid >> 3);      // 256 = 8 XCD-chunks x 32
    const int m0 = (swz >> 3) * 256;                  // 0..31 m-panels
    const int n0 = nbase + (swz & 7) * 128;           // 8 n-panels within z
    gemm8_body<0>(X, ws + OFF_W, ws + OFF_B, qb, kb, vtg, nullptr, m0, n0, sm);
}

// ------------------------------------------------------------------
// 2-wave BK=32 output-projection GEMM (R5 body; measured-passing).
static __device__ __forceinline__ void gemm32_out(
    const u16* __restrict__ X, const u16* __restrict__ W,
    const u16* __restrict__ biasAll, float* __restrict__ Yf,
    int m0, int n0, u16* sm)
{
    constexpr int NT = 32;              // K-tiles of 32
    const int t = threadIdx.x;
    const int wave = t >> 6, lane = t & 63;
    const int quad = lane >> 4, l16 = lane & 15;
    const int rl = lane >> 2;                         // staging row within 16-row group
    const int csrc = (((lane & 3) ^ ((lane >> 3) & 3)) * 8);  // swizzled src col (u16)
    const int swk = (l16 >> 1) & 3;                   // read swizzle key

    f32x4 acc[8][4];
#pragma unroll
    for (int i = 0; i < 8; i++)
#pragma unroll
        for (int j = 0; j < 4; j++) acc[i][j] = (f32x4){0.f, 0.f, 0.f, 0.f};

    auto stage_half = [&](int kt, int bufi, int hf) {
        u16* A = sm + bufi * 8192;      // A: 128x32 u16
        u16* Bb = A + 4096;             // B: 128x32 u16
        const int k0 = kt * 32;
#pragma unroll
        for (int rr = 0; rr < 2; rr++) {
            const int row = hf * 64 + rr * 32 + wave * 16;
            async_ld16(X + (size_t)(m0 + row + rl) * NEMBD + k0 + csrc, &A[row * 32]);
        }
#pragma unroll
        for (int rr = 0; rr < 2; rr++) {
            const int row = hf * 64 + rr * 32 + wave * 16;
            async_ld16(W + (size_t)(n0 + row + rl) * NEMBD + k0 + csrc, &Bb[row * 32]);
        }
    };

    stage_half(0, 0, 0); stage_half(0, 0, 1);
    stage_half(1, 1, 0); stage_half(1, 1, 1);
    asm volatile("s_waitcnt vmcnt(8)" ::: "memory");
    BAR();

    short8 bfr[4], a[4];
    int cb = 0;
    for (int kt = 0; kt < NT; kt++) {
        const int pb = (cb == 0) ? 2 : cb - 1;        // (cb+2)%3
        const u16* A = sm + cb * 8192;
        const u16* Bb = A + 4096;
        const bool pf = kt < NT - 2;

        if (pf) stage_half(kt + 2, pb, 0);
#pragma unroll
        for (int j = 0; j < 4; j++)
            bfr[j] = *(const short8*)&Bb[(wave * 64 + j * 16 + l16) * 32 + ((quad ^ swk) * 8)];
#pragma unroll
        for (int i = 0; i < 4; i++)
            a[i] = *(const short8*)&A[(i * 16 + l16) * 32 + ((quad ^ swk) * 8)];
        __builtin_amdgcn_sched_barrier(0);
        BAR();
        asm volatile("s_waitcnt lgkmcnt(0)" ::: "memory");
        __builtin_amdgcn_sched_barrier(0);
        __builtin_amdgcn_s_setprio(1);
#pragma unroll
        for (int i = 0; i < 4; i++)
#pragma unroll
            for (int j = 0; j < 4; j++)
                acc[i][j] = __builtin_amdgcn_mfma_f32_16x16x32_bf16(a[i], bfr[j], acc[i][j], 0, 0, 0);
        __builtin_amdgcn_s_setprio(0);
        BAR();

        if (pf) stage_half(kt + 2, pb, 1);
#pragma unroll
        for (int i = 0; i < 4; i++)
            a[i] = *(const short8*)&A[((i + 4) * 16 + l16) * 32 + ((quad ^ swk) * 8)];
        __builtin_amdgcn_sched_barrier(0);
        BAR();
        asm volatile("s_waitcnt lgkmcnt(0)" ::: "memory");
        __builtin_amdgcn_sched_barrier(0);
        __builtin_amdgcn_s_setprio(1);
#pragma unroll
        for (int i = 0; i < 4; i++)
#pragma unroll
            for (int j = 0; j < 4; j++)
                acc[i + 4][j] = __builtin_amdgcn_mfma_f32_16x16x32_bf16(a[i], bfr[j], acc[i + 4][j], 0, 0, 0);
        __builtin_amdgcn_s_setprio(0);
        if (pf) asm volatile("s_waitcnt vmcnt(8)" ::: "memory");
        else    asm volatile("s_waitcnt vmcnt(0)" ::: "memory");
        BAR();
        cb = (cb == 2) ? 0 : cb + 1;
    }

#pragma unroll
    for (int j = 0; j < 4; j++) {
        const int n = n0 + wave * 64 + j * 16 + l16;
        const float bn = bf2f(biasAll[n]);
#pragma unroll
        for (int i = 0; i < 8; i++) {
            const int mb = m0 + i * 16 + quad * 4;
#pragma unroll
            for (int r = 0; r < 4; r++)
                Yf[(size_t)(mb + r) * 1024 + n] = acc[i][j][r] + bn;
        }
    }
}

// Output projection: M=8192 x N=1024, 64x8 grid = 512 blocks = 2/CU exact.
__global__ __launch_bounds__(128, 2) void gemm_out9(
    const u16* __restrict__ X, const u16* __restrict__ ws, float* __restrict__ Y)
{
    __shared__ __align__(16) u16 sm[3 * 8192];        // 48 KiB
    const int bid = blockIdx.x;
    const int xcd = bid & 7, i = bid >> 3;            // i in 0..63
    const int mp = xcd * 8 + i / 8;                   // 0..63
    const int np = i % 8;                             // 0..7
    gemm32_out(X, ws + OFF_W + (size_t)3 * (1u << 20), ws + OFF_B + 3 * 1024,
               Y, mp * 128, np * 128, sm);
}

// ------------------------------------------------------------------
// Legacy 128^2 2-phase body -- kept only for the fp32-X fallback path.
template <typename TX, typename TY>
static __device__ __forceinline__ void gemm_body64(
    const TX* __restrict__ X, const u16* __restrict__ W,
    const u16* __restrict__ bias, TY* __restrict__ Y, int vtrans,
    u16* As, u16* Bs)   // each 2 * 128*64 u16 (double-buffered)
{
    constexpr int K = NEMBD, N = NEMBD;
    constexpr int BUF = 128 * 64;
    const int t = threadIdx.x;
    const int wave = t >> 6, lane = t & 63;
    const int quad = lane >> 4, l16 = lane & 15;
    const int flat = blockIdx.x + 8 * blockIdx.y;
    const int swz = (flat & 7) * 64 + (flat >> 3);
    const int m0 = (swz >> 3) * 128, n0 = (swz & 7) * 128;
    const int wm = (wave >> 1) * 64, wn = (wave & 1) * 64;
    const int rsub = lane >> 3;
    const int csw = ((lane & 7) ^ rsub) * 8;
    const int swr = l16 & 7;
    const int frow = t >> 1, fc0 = (t & 1) * 4;

    f32x4 acc[4][4];
#pragma unroll
    for (int i = 0; i < 4; i++)
#pragma unroll
        for (int j = 0; j < 4; j++) acc[i][j] = (f32x4){0.f, 0.f, 0.f, 0.f};

    auto stage = [&](int k0, int bufi) {
        u16* A = As + bufi * BUF;
        u16* Bb = Bs + bufi * BUF;
        if constexpr (__is_same(TX, u16)) {
#pragma unroll
            for (int j = 0; j < 4; j++) {
                const int g = wave * 4 + j;
                async_ld16(X + (size_t)(m0 + g * 8 + rsub) * K + k0 + csw, &A[g * 8 * 64]);
            }
        } else {
#pragma unroll
            for (int c = 0; c < 4; c++) {
                const int lc = fc0 + c;
                float4v f0 = *(const float4v*)&X[(size_t)(m0 + frow) * K + k0 + lc * 8];
                float4v f1 = *(const float4v*)&X[(size_t)(m0 + frow) * K + k0 + lc * 8 + 4];
                __align__(16) u16 tmp[8];
#pragma unroll
                for (int j = 0; j < 4; j++) { tmp[j] = f2bf(f0[j]); tmp[4 + j] = f2bf(f1[j]); }
                *(short8*)&A[frow * 64 + (lc ^ (frow & 7)) * 8] = *(const short8*)tmp;
            }
        }
#pragma unroll
        for (int j = 0; j < 4; j++) {
            const int g = wave * 4 + j;
            async_ld16(W + (size_t)(n0 + g * 8 + rsub) * K + k0 + csw, &Bb[g * 8 * 64]);
        }
    };

    stage(0, 0);
    WAIT_ALL();
    __syncthreads();

    int cur = 0;
    for (int k0 = 0; k0 < K; k0 += 64) {
        if (k0 + 64 < K) stage(k0 + 64, cur ^ 1);
        const u16* A = As + cur * BUF;
        const u16* Bb = Bs + cur * BUF;
#pragma unroll
        for (int h = 0; h < 2; h++) {
            short8 a[4], b[4];
#pragma unroll
            for (int i = 0; i < 4; i++) {
                a[i] = *(const short8*)&A[(wm + i * 16 + l16) * 64 + (((h * 4 + quad) ^ swr) * 8)];
                b[i] = *(const short8*)&Bb[(wn + i * 16 + l16) * 64 + (((h * 4 + quad) ^ swr) * 8)];
            }
#pragma unroll
            for (int i = 0; i < 4; i++)
#pragma unroll
                for (int j = 0; j < 4; j++)
                    acc[i][j] = __builtin_amdgcn_mfma_f32_16x16x32_bf16(a[i], b[j], acc[i][j], 0, 0, 0);
        }
        WAIT_ALL();
        __syncthreads();
        cur ^= 1;
    }

    if (vtrans) {
        u16* VT = (u16*)Y;
#pragma unroll
        for (int j = 0; j < 4; j++) {
            const int n = n0 + wn + j * 16 + l16;
            const float bn = bf2f(bias[n]);
            const int h = n >> 6, d = n & 63;
#pragma unroll
            for (int i = 0; i < 4; i++) {
                const int mb = m0 + wm + i * 16 + quad * 4;
                const int b = mb >> 10, key = mb & 1023;
                us4 pack;
#pragma unroll
                for (int r = 0; r < 4; r++) pack[r] = f2bf(acc[i][j][r] + bn);
                *(us4*)&VT[(size_t)(b * 16 + h) * 65536 + d * 1024 + key] = pack;
            }
        }
    } else {
#pragma unroll
        for (int j = 0; j < 4; j++) {
            const int n = n0 + wn + j * 16 + l16;
            const float bn = bf2f(bias[n]);
#pragma unroll
            for (int i = 0; i < 4; i++) {
                const int mb = m0 + wm + i * 16 + quad * 4;
#pragma unroll
                for (int r = 0; r < 4; r++) {
                    float v = acc[i][j][r] + bn;
                    if constexpr (__is_same(TY, u16)) Y[(size_t)(mb + r) * N + n] = f2bf(v);
                    else                              Y[(size_t)(mb + r) * N + n] = v;
                }
            }
        }
    }
}

// QKV, fp32-X fallback (in-GEMM convert)
__global__ __launch_bounds__(256) void gemm_qkv_f(
    const float* __restrict__ xq, const float* __restrict__ xk, const float* __restrict__ xv,
    const u16* __restrict__ ws, u16* __restrict__ qb, u16* __restrict__ kb,
    u16* __restrict__ vtg)
{
    __shared__ __align__(16) u16 As[2 * 128 * 64];
    __shared__ __align__(16) u16 Bs[2 * 128 * 64];
    const int z = blockIdx.z;
    const float* X = (z == 0) ? xq : (z == 1) ? xk : xv;
    const u16* W = ws + OFF_W + (size_t)z * (1u << 20);
    const u16* bias = ws + OFF_B + z * 1024;
    u16* Y = (z == 0) ? qb : (z == 1) ? kb : vtg;
    gemm_body64<float, u16>(X, W, bias, Y, z == 2 ? 1 : 0, As, Bs);
}

// ------------------------------------------------------------------
// Flash attention v6: SWAPPED QK^T. Computing mfma(K, Q) instead of
// mfma(Q, K) flips the D-layout so a lane holds S[keys quad*4+r][query
// l16] -- 4 CONSECUTIVE keys for one query. The A/B fragments of
// mfma_f32_16x16x32_bf16 have identical per-lane load patterns, so the
// swap costs nothing on loads. Wins vs v5:
//   - P store = 1 us4 (b64) per (m,s) instead of 4 scalar ds_write_u16
//     (4x fewer DS writes, conflict-free)
//   - row-sum = scalar per-lane accumulator + 2 shfl_xor (was 4 vectors)
//   - exp2f with log2(e) pre-folded into Q scale (saves mul per element)
// PV side and Pl layout [q][key] stride-72 unchanged.
__global__ __launch_bounds__(256, 2) void attn_fused(
    const u16* __restrict__ Qp, const u16* __restrict__ Kp,
    const u16* __restrict__ Vtg, u16* __restrict__ Yp)
{
    __shared__ __align__(16) u16 Kl[2][64 * 64];    // [buf][key][d], chunk-swizzled
    __shared__ __align__(16) u16 Vt[2][64 * 64];    // [buf][d][key], chunk-swizzled
    __shared__ __align__(16) u16 Pl[4 * 64 * 72];   // per-wave P: rows 0-31 tile A, 32-63 tile B

    const int t = threadIdx.x;
    const int wave = t >> 6, lane = t & 63;
    const int quad = lane >> 4, l16 = lane & 15;
    const int bh = blockIdx.y;
    const int b = bh >> 4, h = bh & 15;
    const int p = blockIdx.x;                       // pair index 0..3
    const int qtA = p, qtB = 7 - p;
    const int q0A = qtA * 128 + wave * 32;
    const int q0B = qtB * 128 + wave * 32;

    const u16* Qb = Qp + (size_t)b * LL * NEMBD + h * HDIM;
    const u16* Kb = Kp + (size_t)b * LL * NEMBD + h * HDIM;
    const u16* Vb = Vtg + (size_t)bh * 65536;       // [d][key]

    short8 aqA[2][2], aqB[2][2];
#pragma unroll
    for (int m = 0; m < 2; m++) {
        aqA[m][0] = *(const short8*)(Qb + (size_t)(q0A + m * 16 + l16) * NEMBD + quad * 8);
        aqA[m][1] = *(const short8*)(Qb + (size_t)(q0A + m * 16 + l16) * NEMBD + 32 + quad * 8);
        aqB[m][0] = *(const short8*)(Qb + (size_t)(q0B + m * 16 + l16) * NEMBD + quad * 8);
        aqB[m][1] = *(const short8*)(Qb + (size_t)(q0B + m * 16 + l16) * NEMBD + 32 + quad * 8);
    }

    f32x4 accA[2][4], accB[2][4];
#pragma unroll
    for (int m = 0; m < 2; m++)
#pragma unroll
        for (int n = 0; n < 4; n++) {
            accA[m][n] = (f32x4){0.f, 0.f, 0.f, 0.f};
            accB[m][n] = (f32x4){0.f, 0.f, 0.f, 0.f};
        }
    float lsA[2] = {0.f, 0.f};          // per-lane partial row-sum for query l16
    float lsB[2] = {0.f, 0.f};

    const int rsub = lane >> 3;
    const int csw8 = ((lane & 7) ^ rsub) * 8;
    const int swr = l16 & 7;
    u16* pw = &Pl[wave * 64 * 72];

    const int ktiles  = 2 * qtB + 2;
    const int ktilesA = 2 * qtA + 2;

    auto stageKV = [&](int kbase, int bufi) {
#pragma unroll
        for (int j = 0; j < 2; j++) {
            const int g0 = wave * 16 + j * 8;
            async_ld16(Kb + (size_t)(kbase + g0 + rsub) * NEMBD + csw8, &Kl[bufi][g0 * 64]);
            async_ld16(Vb + (size_t)(g0 + rsub) * LL + kbase + csw8, &Vt[bufi][g0 * 64]);
        }
    };

    // swapped QK^T: ss = K_frag x Q_frag -> lane holds S[key=s*16+quad*4+r][q=l16]
    auto qk = [&](const short8 (&aq)[2][2], int q0w, int kbase, const u16* KlC,
                  u16* pwT, float (&lsum)[2]) {
#pragma unroll
        for (int m = 0; m < 2; m++) {
            const int qlo = q0w + m * 16;
            if (kbase > qlo + 15) continue;         // fully masked (wave-uniform)
            const bool dg = (kbase + 63 > qlo);
            const int q = qlo + l16;                // this lane's query
#pragma unroll
            for (int s = 0; s < 4; s++) {
                const int krow = s * 16 + l16;      // A-fragment row (key-within-tile)
                const short8 ak0 = *(const short8*)&KlC[krow * 64 + ((quad ^ swr) * 8)];
                const short8 ak1 = *(const short8*)&KlC[krow * 64 + (((quad + 4) ^ swr) * 8)];
                f32x4 ss = (f32x4){0.f, 0.f, 0.f, 0.f};
                ss = __builtin_amdgcn_mfma_f32_16x16x32_bf16(ak0, aq[m][0], ss, 0, 0, 0);
                ss = __builtin_amdgcn_mfma_f32_16x16x32_bf16(ak1, aq[m][1], ss, 0, 0, 0);
                const int k0l = kbase + s * 16 + quad * 4;  // this lane's first key
                us4 o;
                float part = 0.f;
#pragma unroll
                for (int r = 0; r < 4; r++) {
                    float e = exp2f(ss[r]);
                    if (dg && (k0l + r > q)) e = 0.f;
                    part += e;
                    o[r] = f2bf(e);
                }
                lsum[m] += part;
                *(us4*)&pwT[(m * 16 + l16) * 72 + s * 16 + quad * 4] = o;
            }
        }
    };

    auto pv = [&](f32x4 (&acc)[2][4], int q0w, int kbase, const u16* pwT,
                  const short8 (&bv)[4][2]) {
#pragma unroll
        for (int m = 0; m < 2; m++) {
            if (kbase > q0w + m * 16 + 15) continue;
            const short8 ap0 = *(const short8*)&pwT[(m * 16 + l16) * 72 + quad * 8];
            const short8 ap1 = *(const short8*)&pwT[(m * 16 + l16) * 72 + 32 + quad * 8];
#pragma unroll
            for (int n = 0; n < 4; n++) {
                acc[m][n] = __builtin_amdgcn_mfma_f32_16x16x32_bf16(ap0, bv[n][0], acc[m][n], 0, 0, 0);
                acc[m][n] = __builtin_amdgcn_mfma_f32_16x16x32_bf16(ap1, bv[n][1], acc[m][n], 0, 0, 0);
            }
        }
    };

    stageKV(0, 0);
    WAIT_ALL();
    __syncthreads();

    int cur = 0;
    for (int kt = 0; kt < ktiles; kt++) {
        const int kbase = kt * 64;
        if (kt + 1 < ktiles) stageKV(kbase + 64, cur ^ 1);

        const u16* KlC = &Kl[cur][0];
        const u16* VtC = &Vt[cur][0];

        qk(aqB, q0B, kbase, KlC, pw + 32 * 72, lsB);
        if (kt < ktilesA) qk(aqA, q0A, kbase, KlC, pw, lsA);
        asm volatile("s_waitcnt lgkmcnt(0)" ::: "memory");  // wave-private P write->read

        const bool actB = (kbase <= q0B + 31);
        const bool actA = (kt < ktilesA) && (kbase <= q0A + 31);
        if (actA || actB) {
            short8 bv[4][2];
#pragma unroll
            for (int n = 0; n < 4; n++) {
                const int drow = (n * 16 + l16) * 64;
                bv[n][0] = *(const short8*)&VtC[drow + ((quad ^ swr) * 8)];
                bv[n][1] = *(const short8*)&VtC[drow + (((quad + 4) ^ swr) * 8)];
            }
            __builtin_amdgcn_s_setprio(1);
            if (actB) pv(accB, q0B, kbase, pw + 32 * 72, bv);
            if (actA) pv(accA, q0A, kbase, pw, bv);
            __builtin_amdgcn_s_setprio(0);
        }

        WAIT_ALL();
        __syncthreads();
        cur ^= 1;
    }

    u16* Yb = Yp + (size_t)b * LL * NEMBD + h * HDIM;
    // lsum[m] holds this lane's partial sum for query q0w+m*16+l16 (over its
    // key subset); quads hold disjoint key subsets -> reduce across quads.
    auto epi = [&](f32x4 (&acc)[2][4], float (&lsum)[2], int q0w) {
#pragma unroll
        for (int m = 0; m < 2; m++) {
            float lr = lsum[m];
            lr += __shfl_xor(lr, 16);
            lr += __shfl_xor(lr, 32);               // full sum for query l16
            const float inv = 1.f / lr;
#pragma unroll
            for (int r = 0; r < 4; r++) {
                // acc row quad*4+r = query q0w+m*16+quad*4+r; its inv lives at
                // lanes with l16 == quad*4+r -> pull from lane (quad*4+r).
                const float invr = __shfl(inv, quad * 4 + r);
                const int q = q0w + m * 16 + quad * 4 + r;
#pragma unroll
                for (int n = 0; n < 4; n++)
                    Yb[(size_t)q * NEMBD + n * 16 + l16] = f2bf(acc[m][n][r] * invr);
            }
        }
    };
    epi(accA, lsA, q0A);
    epi(accB, lsB, q0B);
}

// ------------------------------------------------------------------
extern "C" void kernel_launch(void* const* d_in, const int* in_sizes, int n_in,
                              void* d_out, int out_size, void* d_ws, size_t ws_size,
                              hipStream_t stream)
{
    const float* key   = (const float*)d_in[0];
    const float* value = (const float*)d_in[1];
    const float* query = (const float*)d_in[2];
    const float* Wk = (const float*)d_in[3];
    const float* bk = (const float*)d_in[4];
    const float* Wq = (const float*)d_in[5];
    const float* bq = (const float*)d_in[6];
    const float* Wv = (const float*)d_in[7];
    const float* bv = (const float*)d_in[8];
    const float* Wp = (const float*)d_in[9];
    const float* bp = (const float*)d_in[10];

    u16* ws = (u16*)d_ws;
    u16* qb = ws + OFF_QB;                       // Q proj; also attn output (alias-safe)
    u16* kb = (u16*)d_out;                       // K proj in d_out
    u16* vtg = (u16*)d_out + (1u << 23);         // V^T [b][h][d][key] in d_out

    const bool preX = ws_size >= WS_NEED_PRE;    // constant across calls -> graph-safe

    cvt_all<<<2048, 256, 0, stream>>>(
        Wq, Wk, Wv, Wp, bq, bk, bv, bp, query, key, value, ws, preX ? 28676 : 4100);

    if (preX) {
        const u16* xq = ws + OFF_X;
        const u16* xk = ws + OFF_X + (1u << 23);
        const u16* xv = ws + OFF_X + (2u << 23);
        gemm_qkv8z<<<256, 512, 0, stream>>>(xq, ws, qb, kb, vtg, 0);
        gemm_qkv8z<<<256, 512, 0, stream>>>(xk, ws, qb, kb, vtg, 1024);
        gemm_qkv8z<<<256, 512, 0, stream>>>(xv, ws, qb, kb, vtg, 2048);
    } else {
        gemm_qkv_f<<<dim3(8, 64, 3), 256, 0, stream>>>(query, key, value, ws, qb, kb, vtg);
    }

    attn_fused<<<dim3(4, 128), 256, 0, stream>>>(qb, kb, vtg, qb);

    gemm_out9<<<512, 128, 0, stream>>>(qb, ws, (float*)d_out);
}

// Round 10
// 294.451 us; speedup vs baseline: 1.0250x; 1.0066x over previous
//
#include <hip/hip_runtime.h>
#include <cstdint>
#include <cstddef>

typedef unsigned short u16;
typedef __attribute__((ext_vector_type(8))) short short8;      // 8 bf16 (4 VGPRs) MFMA operand
typedef __attribute__((ext_vector_type(4))) float f32x4;       // MFMA 16x16 accumulator
typedef __attribute__((ext_vector_type(4))) float float4v;
typedef __attribute__((ext_vector_type(4))) unsigned short us4;

#define NEMBD 1024
#define NHEADS 16
#define HDIM 64
#define BB 8
#define LL 1024
#define MTOT (BB * LL)

// ---- ws layout (u16 offsets) ----
#define OFF_W 0                       // 4 weight matrices, 1<<20 u16 each (Wq,Wk,Wv,Wp) -- contiguous rows
#define OFF_B (4u << 20)              // 4 biases, 1024 u16 each (bq,bk,bv,bp) -- contiguous
#define OFF_QB (OFF_B + 4096)         // Q projection / attn output, 1<<23 u16
#define OFF_X (OFF_QB + (1u << 23))   // optional bf16 copies of query,key,value
#define WS_NEED_PRE ((size_t)(OFF_X + 3u * (1u << 23)) * 2)  // 75,505,664 B

// Q pre-scale: 1/sqrt(64) * log2(e) -- attn computes 2^x
#define QSCALE 0.18033688f

static __device__ __forceinline__ float bf2f(u16 h) {
    union { unsigned u; float f; } x; x.u = ((unsigned)h) << 16; return x.f;
}
static __device__ __forceinline__ u16 f2bf(float f) {
    union { unsigned u; float f; } x; x.f = f;
    unsigned u = x.u; u += 0x7fffu + ((u >> 16) & 1u);
    return (u16)(u >> 16);
}

// 2^x, single v_exp_f32 WITH compiler-managed TRANS-pipe hazard handling.
// (R9 lesson: inline-asm v_exp_f32 bypasses the hazard recognizer -> the
// consumer can read the result register before the required wait state ->
// stale data. Use the intrinsic/libm path so the compiler inserts the gap.)
static __device__ __forceinline__ float fast_exp2(float x) {
#if defined(__has_builtin)
#if __has_builtin(__builtin_amdgcn_exp2f)
    return __builtin_amdgcn_exp2f(x);
#else
    return exp2f(x);
#endif
#else
    return exp2f(x);
#endif
}

// async global->LDS, 16B per lane; LDS dest = wave-uniform base + lane*16
static __device__ __forceinline__ void async_ld16(const void* g, void* lds_base) {
    __builtin_amdgcn_global_load_lds(
        (const __attribute__((address_space(1))) unsigned int*)g,
        (__attribute__((address_space(3))) unsigned int*)lds_base, 16, 0, 0);
}
#define WAIT_ALL() asm volatile("s_waitcnt vmcnt(0) lgkmcnt(0)" ::: "memory")
#define BAR() __builtin_amdgcn_s_barrier()

// ------------------------------------------------------------------
// fp32 -> bf16 conversion pass. Grid-stride over 1024-elem chunks.
__global__ __launch_bounds__(256) void cvt_all(
    const float* __restrict__ Wq, const float* __restrict__ Wk,
    const float* __restrict__ Wv, const float* __restrict__ Wp,
    const float* __restrict__ bq, const float* __restrict__ bk,
    const float* __restrict__ bv, const float* __restrict__ bp,
    const float* __restrict__ xq, const float* __restrict__ xk,
    const float* __restrict__ xv, u16* __restrict__ ws, int nchunks)
{
    for (int c = blockIdx.x; c < nchunks; c += gridDim.x) {
        int blk = c;
        const float* src; u16* dst; float scale = 1.f;
        if (blk < 1024)      { src = Wq; dst = ws + OFF_W;               scale = QSCALE; }
        else if (blk < 2048) { src = Wk; dst = ws + OFF_W + (1u << 20);  blk -= 1024; }
        else if (blk < 3072) { src = Wv; dst = ws + OFF_W + (2u << 20);  blk -= 2048; }
        else if (blk < 4096) { src = Wp; dst = ws + OFF_W + (3u << 20);  blk -= 3072; }
        else if (blk < 4100) {
            int wb = blk - 4096;
            src = (wb == 0) ? bq : (wb == 1) ? bk : (wb == 2) ? bv : bp;
            dst = ws + OFF_B + wb * 1024; scale = (wb == 0) ? QSCALE : 1.f; blk = 0;
        }
        else if (blk < 12292) { src = xq; dst = ws + OFF_X;               blk -= 4100; }
        else if (blk < 20484) { src = xk; dst = ws + OFF_X + (1u << 23);  blk -= 12292; }
        else                  { src = xv; dst = ws + OFF_X + (2u << 23);  blk -= 20484; }
        const int i = blk * 1024 + threadIdx.x * 4;
        float4v f = *(const float4v*)&src[i];
        us4 o;
#pragma unroll
        for (int j = 0; j < 4; j++) o[j] = f2bf(f[j] * scale);
        *(us4*)&dst[i] = o;
    }
}

// ------------------------------------------------------------------
// 8-wave phase-split GEMM (T3+T4+T5): BM=256, BN=128, BK=64, 512 thr.
// Triple-buffered LDS, counted vmcnt(6), raw s_barrier. MEASURED R3: 66us.
// OUTMODE 0: fused QKV routing (z = n0>>10). OUTMODE 1: fp32 output.
template <int OUTMODE>
static __device__ __forceinline__ void gemm8_body(
    const u16* __restrict__ X, const u16* __restrict__ W,
    const u16* __restrict__ biasAll, u16* __restrict__ qb, u16* __restrict__ kb,
    u16* __restrict__ vtg, float* __restrict__ Yf, int m0, int n0, u16* sm)
{
    constexpr int K = NEMBD;
    constexpr int TILE = 24 * 1024;     // u16: A 256x64 (16K) + B 128x64 (8K)
    constexpr int NT = K / 64;          // 16 K-tiles
    const int t = threadIdx.x;
    const int wave = t >> 6, lane = t & 63;
    const int quad = lane >> 4, l16 = lane & 15;
    const int wm = (wave >> 1) * 64;    // 4 M-groups of waves
    const int wn = (wave & 1) * 64;     // 2 N-groups
    const int rsub = lane >> 3;                 // staging row within 8-row group
    const int csw = ((lane & 7) ^ rsub) * 8;    // swizzled source col (u16)
    const int swr = l16 & 7;                    // read swizzle key

    f32x4 acc[4][4];
#pragma unroll
    for (int i = 0; i < 4; i++)
#pragma unroll
        for (int j = 0; j < 4; j++) acc[i][j] = (f32x4){0.f, 0.f, 0.f, 0.f};

    auto stage_half = [&](int kt, int bufi, int hf) {
        u16* A = sm + bufi * TILE;
        u16* Bb = A + 16 * 1024;
        const int k0 = kt * 64;
#pragma unroll
        for (int j = 0; j < 2; j++) {
            const int g = wave * 4 + hf * 2 + j;          // A: 32 groups of 8 rows
            async_ld16(X + (size_t)(m0 + g * 8 + rsub) * K + k0 + csw, &A[g * 8 * 64]);
        }
        const int gb = wave * 2 + hf;                     // B: 16 groups
        async_ld16(W + (size_t)(n0 + gb * 8 + rsub) * K + k0 + csw, &Bb[gb * 8 * 64]);
    };

    auto phase = [&](int bufi, int h) {
        const u16* A = sm + bufi * TILE;
        const u16* Bb = A + 16 * 1024;
        short8 a[4], b[4];
#pragma unroll
        for (int i = 0; i < 4; i++) {
            a[i] = *(const short8*)&A[(wm + i * 16 + l16) * 64 + (((h * 4 + quad) ^ swr) * 8)];
            b[i] = *(const short8*)&Bb[(wn + i * 16 + l16) * 64 + (((h * 4 + quad) ^ swr) * 8)];
        }
        __builtin_amdgcn_s_setprio(1);
#pragma unroll
        for (int i = 0; i < 4; i++)
#pragma unroll
            for (int j = 0; j < 4; j++)
                acc[i][j] = __builtin_amdgcn_mfma_f32_16x16x32_bf16(a[i], b[j], acc[i][j], 0, 0, 0);
        __builtin_amdgcn_s_setprio(0);
    };

    stage_half(0, 0, 0); stage_half(0, 0, 1);
    stage_half(1, 1, 0); stage_half(1, 1, 1);
    asm volatile("s_waitcnt vmcnt(6)" ::: "memory");
    BAR();

#pragma unroll
    for (int kt = 0; kt < NT; kt++) {
        const int bufi = kt % 3;
        const int nb = (kt + 2) % 3;
        const bool pf = (kt + 2) < NT;
        if (pf) stage_half(kt + 2, nb, 0);
        __builtin_amdgcn_sched_barrier(0);
        phase(bufi, 0);
        BAR();
        if (pf) stage_half(kt + 2, nb, 1);
        __builtin_amdgcn_sched_barrier(0);
        phase(bufi, 1);
        if (pf) asm volatile("s_waitcnt vmcnt(6)" ::: "memory");  // t+1 done, t+2 in flight
        else    asm volatile("s_waitcnt vmcnt(0)" ::: "memory");  // tail drain
        BAR();
    }

    // ---- epilogue. C/D layout: col=lane&15, row=quad*4+reg ----
    if constexpr (OUTMODE == 0) {
        const int nz = n0 >> 10;
        if (nz == 2) {                  // V -> V^T [b][h][d][key]
#pragma unroll
            for (int j = 0; j < 4; j++) {
                const int n = n0 + wn + j * 16 + l16;
                const float bn = bf2f(biasAll[n]);
                const int nl = n & 1023, h = nl >> 6, d = nl & 63;
#pragma unroll
                for (int i = 0; i < 4; i++) {
                    const int mb = m0 + wm + i * 16 + quad * 4;
                    const int b = mb >> 10, key = mb & 1023;
                    us4 pack;
#pragma unroll
                    for (int r = 0; r < 4; r++) pack[r] = f2bf(acc[i][j][r] + bn);
                    *(us4*)&vtg[(size_t)(b * 16 + h) * 65536 + d * 1024 + key] = pack;
                }
            }
        } else {
            u16* Y = (nz == 0) ? qb : kb;
#pragma unroll
            for (int j = 0; j < 4; j++) {
                const int n = n0 + wn + j * 16 + l16;
                const float bn = bf2f(biasAll[n]);
                const int nl = n & 1023;
#pragma unroll
                for (int i = 0; i < 4; i++) {
                    const int mb = m0 + wm + i * 16 + quad * 4;
#pragma unroll
                    for (int r = 0; r < 4; r++)
                        Y[(size_t)(mb + r) * 1024 + nl] = f2bf(acc[i][j][r] + bn);
                }
            }
        }
    } else {
#pragma unroll
        for (int j = 0; j < 4; j++) {
            const int n = n0 + wn + j * 16 + l16;
            const float bn = bf2f(biasAll[n]);
#pragma unroll
            for (int i = 0; i < 4; i++) {
                const int mb = m0 + wm + i * 16 + quad * 4;
#pragma unroll
                for (int r = 0; r < 4; r++)
                    Yf[(size_t)(mb + r) * 1024 + n] = acc[i][j][r] + bn;
            }
        }
    }
}

// Fused QKV: one GEMM M=8192 x N=3072 x K=1024 (Wq/Wk/Wv rows contiguous).
// Grid 768 = 3 exact rounds of 256 CUs (measured best form, R3: 66us).
__global__ __launch_bounds__(512, 1) void gemm_qkv8(
    const u16* __restrict__ xq, const u16* __restrict__ xk, const u16* __restrict__ xv,
    const u16* __restrict__ ws, u16* __restrict__ qb, u16* __restrict__ kb,
    u16* __restrict__ vtg)
{
    __shared__ __align__(16) u16 sm[3 * 24 * 1024];   // 144 KiB
    const int bid = blockIdx.x;
    const int swz = (bid & 7) * 96 + (bid >> 3);      // 768 = 8 XCD-chunks x 96
    const int m0 = (swz / 24) * 256;
    const int np = swz % 24;
    const int n0 = np * 128;
    const int nz = n0 >> 10;
    const u16* X = (nz == 0) ? xq : (nz == 1) ? xk : xv;
    gemm8_body<0>(X, ws + OFF_W, ws + OFF_B, qb, kb, vtg, nullptr, m0, n0, sm);
}

// ------------------------------------------------------------------
// 2-wave BK=32 output-projection GEMM (measured-passing).
static __device__ __forceinline__ void gemm32_out(
    const u16* __restrict__ X, const u16* __restrict__ W,
    const u16* __restrict__ biasAll, float* __restrict__ Yf,
    int m0, int n0, u16* sm)
{
    constexpr int NT = 32;              // K-tiles of 32
    const int t = threadIdx.x;
    const int wave = t >> 6, lane = t & 63;
    const int quad = lane >> 4, l16 = lane & 15;
    const int rl = lane >> 2;                         // staging row within 16-row group
    const int csrc = (((lane & 3) ^ ((lane >> 3) & 3)) * 8);  // swizzled src col (u16)
    const int swk = (l16 >> 1) & 3;                   // read swizzle key

    f32x4 acc[8][4];
#pragma unroll
    for (int i = 0; i < 8; i++)
#pragma unroll
        for (int j = 0; j < 4; j++) acc[i][j] = (f32x4){0.f, 0.f, 0.f, 0.f};

    auto stage_half = [&](int kt, int bufi, int hf) {
        u16* A = sm + bufi * 8192;      // A: 128x32 u16
        u16* Bb = A + 4096;             // B: 128x32 u16
        const int k0 = kt * 32;
#pragma unroll
        for (int rr = 0; rr < 2; rr++) {
            const int row = hf * 64 + rr * 32 + wave * 16;
            async_ld16(X + (size_t)(m0 + row + rl) * NEMBD + k0 + csrc, &A[row * 32]);
        }
#pragma unroll
        for (int rr = 0; rr < 2; rr++) {
            const int row = hf * 64 + rr * 32 + wave * 16;
            async_ld16(W + (size_t)(n0 + row + rl) * NEMBD + k0 + csrc, &Bb[row * 32]);
        }
    };

    stage_half(0, 0, 0); stage_half(0, 0, 1);
    stage_half(1, 1, 0); stage_half(1, 1, 1);
    asm volatile("s_waitcnt vmcnt(8)" ::: "memory");
    BAR();

    short8 bfr[4], a[4];
    int cb = 0;
    for (int kt = 0; kt < NT; kt++) {
        const int pb = (cb == 0) ? 2 : cb - 1;        // (cb+2)%3
        const u16* A = sm + cb * 8192;
        const u16* Bb = A + 4096;
        const bool pf = kt < NT - 2;

        if (pf) stage_half(kt + 2, pb, 0);
#pragma unroll
        for (int j = 0; j < 4; j++)
            bfr[j] = *(const short8*)&Bb[(wave * 64 + j * 16 + l16) * 32 + ((quad ^ swk) * 8)];
#pragma unroll
        for (int i = 0; i < 4; i++)
            a[i] = *(const short8*)&A[(i * 16 + l16) * 32 + ((quad ^ swk) * 8)];
        __builtin_amdgcn_sched_barrier(0);
        BAR();
        asm volatile("s_waitcnt lgkmcnt(0)" ::: "memory");
        __builtin_amdgcn_sched_barrier(0);
        __builtin_amdgcn_s_setprio(1);
#pragma unroll
        for (int i = 0; i < 4; i++)
#pragma unroll
            for (int j = 0; j < 4; j++)
                acc[i][j] = __builtin_amdgcn_mfma_f32_16x16x32_bf16(a[i], bfr[j], acc[i][j], 0, 0, 0);
        __builtin_amdgcn_s_setprio(0);
        BAR();

        if (pf) stage_half(kt + 2, pb, 1);
#pragma unroll
        for (int i = 0; i < 4; i++)
            a[i] = *(const short8*)&A[((i + 4) * 16 + l16) * 32 + ((quad ^ swk) * 8)];
        __builtin_amdgcn_sched_barrier(0);
        BAR();
        asm volatile("s_waitcnt lgkmcnt(0)" ::: "memory");
        __builtin_amdgcn_sched_barrier(0);
        __builtin_amdgcn_s_setprio(1);
#pragma unroll
        for (int i = 0; i < 4; i++)
#pragma unroll
            for (int j = 0; j < 4; j++)
                acc[i + 4][j] = __builtin_amdgcn_mfma_f32_16x16x32_bf16(a[i], bfr[j], acc[i + 4][j], 0, 0, 0);
        __builtin_amdgcn_s_setprio(0);
        if (pf) asm volatile("s_waitcnt vmcnt(8)" ::: "memory");
        else    asm volatile("s_waitcnt vmcnt(0)" ::: "memory");
        BAR();
        cb = (cb == 2) ? 0 : cb + 1;
    }

#pragma unroll
    for (int j = 0; j < 4; j++) {
        const int n = n0 + wave * 64 + j * 16 + l16;
        const float bn = bf2f(biasAll[n]);
#pragma unroll
        for (int i = 0; i < 8; i++) {
            const int mb = m0 + i * 16 + quad * 4;
#pragma unroll
            for (int r = 0; r < 4; r++)
                Yf[(size_t)(mb + r) * 1024 + n] = acc[i][j][r] + bn;
        }
    }
}

// Output projection: M=8192 x N=1024, 64x8 grid = 512 blocks = 2/CU exact.
__global__ __launch_bounds__(128, 2) void gemm_out9(
    const u16* __restrict__ X, const u16* __restrict__ ws, float* __restrict__ Y)
{
    __shared__ __align__(16) u16 sm[3 * 8192];        // 48 KiB
    const int bid = blockIdx.x;
    const int xcd = bid & 7, i = bid >> 3;            // i in 0..63
    const int mp = xcd * 8 + i / 8;                   // 0..63
    const int np = i % 8;                             // 0..7
    gemm32_out(X, ws + OFF_W + (size_t)3 * (1u << 20), ws + OFF_B + 3 * 1024,
               Y, mp * 128, np * 128, sm);
}

// ------------------------------------------------------------------
// Legacy 128^2 2-phase body -- kept only for the fp32-X fallback path.
template <typename TX, typename TY>
static __device__ __forceinline__ void gemm_body64(
    const TX* __restrict__ X, const u16* __restrict__ W,
    const u16* __restrict__ bias, TY* __restrict__ Y, int vtrans,
    u16* As, u16* Bs)   // each 2 * 128*64 u16 (double-buffered)
{
    constexpr int K = NEMBD, N = NEMBD;
    constexpr int BUF = 128 * 64;
    const int t = threadIdx.x;
    const int wave = t >> 6, lane = t & 63;
    const int quad = lane >> 4, l16 = lane & 15;
    const int flat = blockIdx.x + 8 * blockIdx.y;
    const int swz = (flat & 7) * 64 + (flat >> 3);
    const int m0 = (swz >> 3) * 128, n0 = (swz & 7) * 128;
    const int wm = (wave >> 1) * 64, wn = (wave & 1) * 64;
    const int rsub = lane >> 3;
    const int csw = ((lane & 7) ^ rsub) * 8;
    const int swr = l16 & 7;
    const int frow = t >> 1, fc0 = (t & 1) * 4;

    f32x4 acc[4][4];
#pragma unroll
    for (int i = 0; i < 4; i++)
#pragma unroll
        for (int j = 0; j < 4; j++) acc[i][j] = (f32x4){0.f, 0.f, 0.f, 0.f};

    auto stage = [&](int k0, int bufi) {
        u16* A = As + bufi * BUF;
        u16* Bb = Bs + bufi * BUF;
        if constexpr (__is_same(TX, u16)) {
#pragma unroll
            for (int j = 0; j < 4; j++) {
                const int g = wave * 4 + j;
                async_ld16(X + (size_t)(m0 + g * 8 + rsub) * K + k0 + csw, &A[g * 8 * 64]);
            }
        } else {
#pragma unroll
            for (int c = 0; c < 4; c++) {
                const int lc = fc0 + c;
                float4v f0 = *(const float4v*)&X[(size_t)(m0 + frow) * K + k0 + lc * 8];
                float4v f1 = *(const float4v*)&X[(size_t)(m0 + frow) * K + k0 + lc * 8 + 4];
                __align__(16) u16 tmp[8];
#pragma unroll
                for (int j = 0; j < 4; j++) { tmp[j] = f2bf(f0[j]); tmp[4 + j] = f2bf(f1[j]); }
                *(short8*)&A[frow * 64 + (lc ^ (frow & 7)) * 8] = *(const short8*)tmp;
            }
        }
#pragma unroll
        for (int j = 0; j < 4; j++) {
            const int g = wave * 4 + j;
            async_ld16(W + (size_t)(n0 + g * 8 + rsub) * K + k0 + csw, &Bb[g * 8 * 64]);
        }
    };

    stage(0, 0);
    WAIT_ALL();
    __syncthreads();

    int cur = 0;
    for (int k0 = 0; k0 < K; k0 += 64) {
        if (k0 + 64 < K) stage(k0 + 64, cur ^ 1);
        const u16* A = As + cur * BUF;
        const u16* Bb = Bs + cur * BUF;
#pragma unroll
        for (int h = 0; h < 2; h++) {
            short8 a[4], b[4];
#pragma unroll
            for (int i = 0; i < 4; i++) {
                a[i] = *(const short8*)&A[(wm + i * 16 + l16) * 64 + (((h * 4 + quad) ^ swr) * 8)];
                b[i] = *(const short8*)&Bb[(wn + i * 16 + l16) * 64 + (((h * 4 + quad) ^ swr) * 8)];
            }
#pragma unroll
            for (int i = 0; i < 4; i++)
#pragma unroll
                for (int j = 0; j < 4; j++)
                    acc[i][j] = __builtin_amdgcn_mfma_f32_16x16x32_bf16(a[i], b[j], acc[i][j], 0, 0, 0);
        }
        WAIT_ALL();
        __syncthreads();
        cur ^= 1;
    }

    if (vtrans) {
        u16* VT = (u16*)Y;
#pragma unroll
        for (int j = 0; j < 4; j++) {
            const int n = n0 + wn + j * 16 + l16;
            const float bn = bf2f(bias[n]);
            const int h = n >> 6, d = n & 63;
#pragma unroll
            for (int i = 0; i < 4; i++) {
                const int mb = m0 + wm + i * 16 + quad * 4;
                const int b = mb >> 10, key = mb & 1023;
                us4 pack;
#pragma unroll
                for (int r = 0; r < 4; r++) pack[r] = f2bf(acc[i][j][r] + bn);
                *(us4*)&VT[(size_t)(b * 16 + h) * 65536 + d * 1024 + key] = pack;
            }
        }
    } else {
#pragma unroll
        for (int j = 0; j < 4; j++) {
            const int n = n0 + wn + j * 16 + l16;
            const float bn = bf2f(bias[n]);
#pragma unroll
            for (int i = 0; i < 4; i++) {
                const int mb = m0 + wm + i * 16 + quad * 4;
#pragma unroll
                for (int r = 0; r < 4; r++) {
                    float v = acc[i][j][r] + bn;
                    if constexpr (__is_same(TY, u16)) Y[(size_t)(mb + r) * N + n] = f2bf(v);
                    else                              Y[(size_t)(mb + r) * N + n] = v;
                }
            }
        }
    }
}

// QKV, fp32-X fallback (in-GEMM convert)
__global__ __launch_bounds__(256) void gemm_qkv_f(
    const float* __restrict__ xq, const float* __restrict__ xk, const float* __restrict__ xv,
    const u16* __restrict__ ws, u16* __restrict__ qb, u16* __restrict__ kb,
    u16* __restrict__ vtg)
{
    __shared__ __align__(16) u16 As[2 * 128 * 64];
    __shared__ __align__(16) u16 Bs[2 * 128 * 64];
    const int z = blockIdx.z;
    const float* X = (z == 0) ? xq : (z == 1) ? xk : xv;
    const u16* W = ws + OFF_W + (size_t)z * (1u << 20);
    const u16* bias = ws + OFF_B + z * 1024;
    u16* Y = (z == 0) ? qb : (z == 1) ? kb : vtg;
    gemm_body64<float, u16>(X, W, bias, Y, z == 2 ? 1 : 0, As, Bs);
}

// ------------------------------------------------------------------
// Flash attention v7b: swapped QK^T (verified R8) + swizzled Pl (bank
// geometry verified by hand, R9) + intrinsic exp2 (R9 fix: no inline-asm
// v_exp_f32 -- TRANS hazard must be compiler-managed).
//  - Pl: 64-u16 rows, XOR-16B-chunk swizzle (same scheme as Kl/Vt)
//  - store: us4 at chunk (s*2+(quad>>1))^(l16&7), half quad&1 -> balanced
//  - read: short8 at chunk (quad / quad+4)^(l16&7) -> balanced
// LDS 64 KB, 2 blocks/CU.
__global__ __launch_bounds__(256, 2) void attn_fused(
    const u16* __restrict__ Qp, const u16* __restrict__ Kp,
    const u16* __restrict__ Vtg, u16* __restrict__ Yp)
{
    __shared__ __align__(16) u16 Kl[2][64 * 64];    // [buf][key][d], chunk-swizzled
    __shared__ __align__(16) u16 Vt[2][64 * 64];    // [buf][d][key], chunk-swizzled
    __shared__ __align__(16) u16 Pl[4 * 64 * 64];   // per-wave P, chunk-swizzled, rows 0-31 A / 32-63 B

    const int t = threadIdx.x;
    const int wave = t >> 6, lane = t & 63;
    const int quad = lane >> 4, l16 = lane & 15;
    const int bh = blockIdx.y;
    const int b = bh >> 4, h = bh & 15;
    const int p = blockIdx.x;                       // pair index 0..3
    const int qtA = p, qtB = 7 - p;
    const int q0A = qtA * 128 + wave * 32;
    const int q0B = qtB * 128 + wave * 32;

    const u16* Qb = Qp + (size_t)b * LL * NEMBD + h * HDIM;
    const u16* Kb = Kp + (size_t)b * LL * NEMBD + h * HDIM;
    const u16* Vb = Vtg + (size_t)bh * 65536;       // [d][key]

    short8 aqA[2][2], aqB[2][2];
#pragma unroll
    for (int m = 0; m < 2; m++) {
        aqA[m][0] = *(const short8*)(Qb + (size_t)(q0A + m * 16 + l16) * NEMBD + quad * 8);
        aqA[m][1] = *(const short8*)(Qb + (size_t)(q0A + m * 16 + l16) * NEMBD + 32 + quad * 8);
        aqB[m][0] = *(const short8*)(Qb + (size_t)(q0B + m * 16 + l16) * NEMBD + quad * 8);
        aqB[m][1] = *(const short8*)(Qb + (size_t)(q0B + m * 16 + l16) * NEMBD + 32 + quad * 8);
    }

    f32x4 accA[2][4], accB[2][4];
#pragma unroll
    for (int m = 0; m < 2; m++)
#pragma unroll
        for (int n = 0; n < 4; n++) {
            accA[m][n] = (f32x4){0.f, 0.f, 0.f, 0.f};
            accB[m][n] = (f32x4){0.f, 0.f, 0.f, 0.f};
        }
    float lsA[2] = {0.f, 0.f};          // per-lane partial row-sum for query l16
    float lsB[2] = {0.f, 0.f};

    const int rsub = lane >> 3;
    const int csw8 = ((lane & 7) ^ rsub) * 8;
    const int swr = l16 & 7;
    u16* pw = &Pl[wave * 64 * 64];

    const int ktiles  = 2 * qtB + 2;
    const int ktilesA = 2 * qtA + 2;

    auto stageKV = [&](int kbase, int bufi) {
#pragma unroll
        for (int j = 0; j < 2; j++) {
            const int g0 = wave * 16 + j * 8;
            async_ld16(Kb + (size_t)(kbase + g0 + rsub) * NEMBD + csw8, &Kl[bufi][g0 * 64]);
            async_ld16(Vb + (size_t)(g0 + rsub) * LL + kbase + csw8, &Vt[bufi][g0 * 64]);
        }
    };

    // swapped QK^T: ss = K_frag x Q_frag -> lane holds S[key=s*16+quad*4+r][q=l16]
    auto qk = [&](const short8 (&aq)[2][2], int q0w, int kbase, const u16* KlC,
                  u16* pwT, float (&lsum)[2]) {
#pragma unroll
        for (int m = 0; m < 2; m++) {
            const int qlo = q0w + m * 16;
            if (kbase > qlo + 15) continue;         // fully masked (wave-uniform)
            const bool dg = (kbase + 63 > qlo);
            const int q = qlo + l16;                // this lane's query
#pragma unroll
            for (int s = 0; s < 4; s++) {
                const int krow = s * 16 + l16;      // A-fragment row (key-within-tile)
                const short8 ak0 = *(const short8*)&KlC[krow * 64 + ((quad ^ swr) * 8)];
                const short8 ak1 = *(const short8*)&KlC[krow * 64 + (((quad + 4) ^ swr) * 8)];
                f32x4 ss = (f32x4){0.f, 0.f, 0.f, 0.f};
                ss = __builtin_amdgcn_mfma_f32_16x16x32_bf16(ak0, aq[m][0], ss, 0, 0, 0);
                ss = __builtin_amdgcn_mfma_f32_16x16x32_bf16(ak1, aq[m][1], ss, 0, 0, 0);
                const int k0l = kbase + s * 16 + quad * 4;  // this lane's first key
                us4 o;
                float part = 0.f;
#pragma unroll
                for (int r = 0; r < 4; r++) {
                    float e = fast_exp2(ss[r]);
                    if (dg && (k0l + r > q)) e = 0.f;
                    part += e;
                    o[r] = f2bf(e);
                }
                lsum[m] += part;
                // swizzled store: 16B-chunk (s*2+(quad>>1)) ^ (l16&7), 8B-half quad&1
                const int chs = ((s * 2 + (quad >> 1)) ^ swr) * 8 + (quad & 1) * 4;
                *(us4*)&pwT[(m * 16 + l16) * 64 + chs] = o;
            }
        }
    };

    auto pv = [&](f32x4 (&acc)[2][4], int q0w, int kbase, const u16* pwT,
                  const short8 (&bv)[4][2]) {
#pragma unroll
        for (int m = 0; m < 2; m++) {
            if (kbase > q0w + m * 16 + 15) continue;
            const short8 ap0 = *(const short8*)&pwT[(m * 16 + l16) * 64 + ((quad ^ swr) * 8)];
            const short8 ap1 = *(const short8*)&pwT[(m * 16 + l16) * 64 + (((quad + 4) ^ swr) * 8)];
#pragma unroll
            for (int n = 0; n < 4; n++) {
                acc[m][n] = __builtin_amdgcn_mfma_f32_16x16x32_bf16(ap0, bv[n][0], acc[m][n], 0, 0, 0);
                acc[m][n] = __builtin_amdgcn_mfma_f32_16x16x32_bf16(ap1, bv[n][1], acc[m][n], 0, 0, 0);
            }
        }
    };

    stageKV(0, 0);
    WAIT_ALL();
    __syncthreads();

    int cur = 0;
    for (int kt = 0; kt < ktiles; kt++) {
        const int kbase = kt * 64;
        if (kt + 1 < ktiles) stageKV(kbase + 64, cur ^ 1);

        const u16* KlC = &Kl[cur][0];
        const u16* VtC = &Vt[cur][0];

        qk(aqB, q0B, kbase, KlC, pw + 32 * 64, lsB);
        if (kt < ktilesA) qk(aqA, q0A, kbase, KlC, pw, lsA);
        asm volatile("s_waitcnt lgkmcnt(0)" ::: "memory");  // wave-private P write->read

        const bool actB = (kbase <= q0B + 31);
        const bool actA = (kt < ktilesA) && (kbase <= q0A + 31);
        if (actA || actB) {
            short8 bv[4][2];
#pragma unroll
            for (int n = 0; n < 4; n++) {
                const int drow = (n * 16 + l16) * 64;
                bv[n][0] = *(const short8*)&VtC[drow + ((quad ^ swr) * 8)];
                bv[n][1] = *(const short8*)&VtC[drow + (((quad + 4) ^ swr) * 8)];
            }
            __builtin_amdgcn_s_setprio(1);
            if (actB) pv(accB, q0B, kbase, pw + 32 * 64, bv);
            if (actA) pv(accA, q0A, kbase, pw, bv);
            __builtin_amdgcn_s_setprio(0);
        }

        WAIT_ALL();
        __syncthreads();
        cur ^= 1;
    }

    u16* Yb = Yp + (size_t)b * LL * NEMBD + h * HDIM;
    // lsum[m] holds this lane's partial sum for query q0w+m*16+l16 (over its
    // key subset); quads hold disjoint key subsets -> reduce across quads.
    auto epi = [&](f32x4 (&acc)[2][4], float (&lsum)[2], int q0w) {
#pragma unroll
        for (int m = 0; m < 2; m++) {
            float lr = lsum[m];
            lr += __shfl_xor(lr, 16);
            lr += __shfl_xor(lr, 32);               // full sum for query l16
            const float inv = 1.f / lr;
#pragma unroll
            for (int r = 0; r < 4; r++) {
                // acc row quad*4+r = query q0w+m*16+quad*4+r; its inv lives at
                // lanes with l16 == quad*4+r -> pull from lane (quad*4+r).
                const float invr = __shfl(inv, quad * 4 + r);
                const int q = q0w + m * 16 + quad * 4 + r;
#pragma unroll
                for (int n = 0; n < 4; n++)
                    Yb[(size_t)q * NEMBD + n * 16 + l16] = f2bf(acc[m][n][r] * invr);
            }
        }
    };
    epi(accA, lsA, q0A);
    epi(accB, lsB, q0B);
}

// ------------------------------------------------------------------
extern "C" void kernel_launch(void* const* d_in, const int* in_sizes, int n_in,
                              void* d_out, int out_size, void* d_ws, size_t ws_size,
                              hipStream_t stream)
{
    const float* key   = (const float*)d_in[0];
    const float* value = (const float*)d_in[1];
    const float* query = (const float*)d_in[2];
    const float* Wk = (const float*)d_in[3];
    const float* bk = (const float*)d_in[4];
    const float* Wq = (const float*)d_in[5];
    const float* bq = (const float*)d_in[6];
    const float* Wv = (const float*)d_in[7];
    const float* bv = (const float*)d_in[8];
    const float* Wp = (const float*)d_in[9];
    const float* bp = (const float*)d_in[10];

    u16* ws = (u16*)d_ws;
    u16* qb = ws + OFF_QB;                       // Q proj; also attn output (alias-safe)
    u16* kb = (u16*)d_out;                       // K proj in d_out
    u16* vtg = (u16*)d_out + (1u << 23);         // V^T [b][h][d][key] in d_out

    const bool preX = ws_size >= WS_NEED_PRE;    // constant across calls -> graph-safe

    cvt_all<<<2048, 256, 0, stream>>>(
        Wq, Wk, Wv, Wp, bq, bk, bv, bp, query, key, value, ws, preX ? 28676 : 4100);

    if (preX) {
        const u16* xq = ws + OFF_X;
        const u16* xk = ws + OFF_X + (1u << 23);
        const u16* xv = ws + OFF_X + (2u << 23);
        gemm_qkv8<<<768, 512, 0, stream>>>(xq, xk, xv, ws, qb, kb, vtg);
    } else {
        gemm_qkv_f<<<dim3(8, 64, 3), 256, 0, stream>>>(query, key, value, ws, qb, kb, vtg);
    }

    attn_fused<<<dim3(4, 128), 256, 0, stream>>>(qb, kb, vtg, qb);

    gemm_out9<<<512, 128, 0, stream>>>(qb, ws, (float*)d_out);
}